// Round 11
// baseline (94.164 us; speedup 1.0000x reference)
//
#include <hip/hip_runtime.h>
#include <math.h>

#define XD 128
#define YD 128
#define ZD 96
#define NV (XD*YD*ZD)      /* 1572864 voxels per volume */
#define SXX (YD*ZD)        /* x-stride = 12288 */
#define SENT 49152         /* sentinel: > any real d^2 (max 41283) */
#define TW2 114            /* u16 cols: 8 pad | 96 z | 10 pad; 57 dw, 57%32=25 */
#define TDW (TW2/2)        /* 57 dwords per row */
#define TROWS 144          /* rows: 8 pad | 128 y | 8 pad */

// ---------------------------------------------------------------- flags ----
__global__ void k_zero_flags(int* flags) {
    if (threadIdx.x < 8) flags[threadIdx.x] = 0;
}

// -------------------------------------------- pass X: binary run-length scan
// 6 waves: wave w6 = 2*c+s owns the (class c+1, sign s) scan for all 64 lines.
// Register-resident scan; in-wave 4x4 byte transpose for the output.
__global__ __launch_bounds__(384) void k_scan_x(const int* __restrict__ gt,
                                                unsigned char* __restrict__ out,
                                                int* __restrict__ flags,
                                                int batch0) {
    const int bb  = blockIdx.y;
    const int myb = batch0 + bb;
    const int tid = threadIdx.x;
    const int l   = tid & 63;
    const int w6  = tid >> 6;            // 0..5
    const int lq0 = blockIdx.x * 64;

    __shared__ unsigned char gtile[64 * 132];
    __shared__ int blkbits;
    if (tid == 0) blkbits = 0;

    int mybits = 0;
    const int* gp = gt + (size_t)myb * NV + lq0 + l;
    for (int j = w6; j < XD; j += 6) {
        int g = gp[(size_t)j * SXX];
        mybits |= 1 << g;
        gtile[l * 132 + j] = (unsigned char)g;
    }
#pragma unroll
    for (int off = 32; off; off >>= 1) mybits |= __shfl_xor(mybits, off);
    __syncthreads();
    if ((tid & 63) == 0) atomicOr(&blkbits, mybits);

    unsigned int D[32];
    {   // thread = (slot w6, line l); slot = 2*c + s; all in registers
        const unsigned int ci = (unsigned int)((w6 >> 1) + 1);
        const int s = w6 & 1;
        unsigned int G[32];
        const unsigned int* grow = (const unsigned int*)gtile + l * 33;
#pragma unroll
        for (int q = 0; q < 32; ++q) G[q] = grow[q];

        int cnt = 200;
#pragma unroll
        for (int q = 0; q < 32; ++q) {
            unsigned int u = G[q], dv = 0;
#pragma unroll
            for (int b = 0; b < 4; ++b) {
                unsigned int gv = (u >> (8 * b)) & 255u;
                bool zero = s ? (gv == ci) : (gv != ci);
                cnt = zero ? 0 : ((cnt < 200) ? cnt + 1 : 200);
                dv |= (unsigned int)cnt << (8 * b);
            }
            D[q] = dv;
        }
        cnt = 200;
#pragma unroll
        for (int q = 31; q >= 0; --q) {
            unsigned int u = G[q], dv = D[q];
#pragma unroll
            for (int b = 3; b >= 0; --b) {
                unsigned int gv = (u >> (8 * b)) & 255u;
                bool zero = s ? (gv == ci) : (gv != ci);
                cnt = zero ? 0 : ((cnt < 200) ? cnt + 1 : 200);
                unsigned int old = (dv >> (8 * b)) & 255u;
                unsigned int nbv = ((unsigned int)cnt < old) ? (unsigned int)cnt : old;
                dv = (dv & ~(255u << (8 * b))) | (nbv << (8 * b));
            }
            D[q] = dv;
        }
    }
    __syncthreads();                     // blkbits complete
    if (tid == 0) atomicOr(&flags[myb], blkbits);

    // in-wave 4x4 byte transpose (groups of 4 lanes = 4 lines) + store
    {
        const int r = l & 3;
        unsigned char* ob = out + (size_t)(bb * 6 + w6) * NV + lq0 + (l & ~3);
#pragma unroll
        for (int q = 0; q < 32; ++q) {
            unsigned int A = D[q];
            unsigned int Bv = (unsigned int)__shfl_xor((int)A, 1);
            unsigned int t = (r & 1)
                ? __builtin_amdgcn_perm(A, Bv, 0x07030501u)
                : __builtin_amdgcn_perm(A, Bv, 0x02060004u);
            unsigned int Cv = (unsigned int)__shfl_xor((int)t, 2);
            unsigned int y = (r & 2)
                ? __builtin_amdgcn_perm(t, Cv, 0x07060302u)
                : __builtin_amdgcn_perm(t, Cv, 0x01000504u);
            *(unsigned int*)(ob + (size_t)(4 * q + r) * SXX) = y;
        }
    }
}

// ------------- EDT fast path: t<=8 on a 24-float register window -----------
// 8 outputs, centers at r[8..15]. Bit-exact vs brute force.
__device__ __forceinline__ bool edt_fast8(const float r[24], float m[8]) {
#pragma unroll
    for (int k = 0; k < 8; ++k) m[k] = r[k + 8];
#pragma unroll
    for (int t = 1; t <= 4; ++t) {
        const float t2 = (float)(t * t);
#pragma unroll
        for (int k = 0; k < 8; ++k)
            m[k] = fminf(m[k], fminf(r[k + 8 - t], r[k + 8 + t]) + t2);
    }
    float mm = m[0];
#pragma unroll
    for (int k = 1; k < 8; ++k) mm = fmaxf(mm, m[k]);
    if (__all(mm <= 16.0f)) return true;
#pragma unroll
    for (int t = 5; t <= 8; ++t) {
        const float t2 = (float)(t * t);
#pragma unroll
        for (int k = 0; k < 8; ++k)
            m[k] = fminf(m[k], fminf(r[k + 8 - t], r[k + 8 + t]) + t2);
    }
    mm = m[0];
#pragma unroll
    for (int k = 1; k < 8; ++k) mm = fmaxf(mm, m[k]);
    return __all(mm <= 64.0f) != 0;
}

// ------------- EDT slow path (rare): clamped LDS u16 reads, t>=9 -----------
// p0 points at element j=0 (value at j is p0[j*STRIDE]); valid j in [-8,L+7].
template<int STRIDE, int L>
__device__ void edt_slow8(const unsigned short* __restrict__ p0, int i0,
                          float m[8]) {
    int t = 9;
    bool done = false;
    while (!done && t < L) {
        for (int u = 0; u < 4; ++u, ++t) {
            float t2 = (float)(t * t);
#pragma unroll
            for (int k = 0; k < 8; ++k) {
                int jm = i0 + k - t; if (jm < -8) jm = -8;
                int jp = i0 + k + t; if (jp > L + 7) jp = L + 7;
                m[k] = fminf(m[k], fminf((float)p0[jm * STRIDE],
                                         (float)p0[jp * STRIDE]) + t2);
            }
        }
        float mm = m[0];
#pragma unroll
        for (int k = 1; k < 8; ++k) mm = fmaxf(mm, m[k]);
        done = __all(mm <= (float)((t - 1) * (t - 1))) != 0;
    }
}

// ---- one 8-output chunk along y (fixed z), window read column-wise --------
__device__ __forceinline__ void chunkY(const unsigned short* __restrict__ tile,
                                       int z, int i0, float m[8]) {
    float r[24];
#pragma unroll
    for (int w = 0; w < 24; ++w) r[w] = (float)tile[(i0 + w) * TW2 + 8 + z];
    if (!edt_fast8(r, m)) edt_slow8<TW2, YD>(&tile[8 * TW2 + 8 + z], i0, m);
}

// ---- one 8-output chunk along z (fixed y), window read dword-packed -------
__device__ __forceinline__ void chunkZ(const unsigned short* __restrict__ tile,
                                       const unsigned int* __restrict__ t32,
                                       int y, int i0, float m[8]) {
    float r[24];
    const unsigned int* wp = &t32[(8 + y) * TDW + i0 / 2];
#pragma unroll
    for (int q = 0; q < 12; ++q) {
        unsigned int u = wp[q];
        r[2 * q] = (float)(u & 0xFFFFu);
        r[2 * q + 1] = (float)(u >> 16);
    }
    if (!edt_fast8(r, m)) edt_slow8<1, ZD>(&tile[(8 + y) * TW2 + 8], i0, m);
}

// ------------- fused Y+Z pass: x-plane in LDS as u16 [y][z] ----------------
// Tile [144 rows = 8|128y|8][114 cols = 8|96z|10] u16. 8-output chunks,
// 4 per thread per phase (holds 4x m[8] across the barrier; ~60 live VGPRs,
// no spills). All accesses bank-conflict-free by construction.
__global__ __launch_bounds__(384, 4) void k_pass_yz(const unsigned char* __restrict__ in,
                                                    unsigned short* __restrict__ out) {
    const int lv  = blockIdx.y;          // volume slot
    const int x   = blockIdx.x;
    const int tid = threadIdx.x;
    __shared__ unsigned short tile[TROWS * TW2];
    unsigned int* t32 = (unsigned int*)tile;

    // pad rows (y pads): rows 0..7 and 136..143, full width
    for (int i = tid; i < 16 * TDW; i += 384) {
        int r = i / TDW, c = i - r * TDW;
        int row = (r < 8) ? r : 128 + r;
        t32[row * TDW + c] = 0xFFFFFFFFu;
    }
    // pad cols in data rows: dwords 0..3 (left) and 52..56 (right)
    for (int i = tid; i < 128 * 9; i += 384) {
        int r = i / 9, c = i - r * 9;
        int col = (c < 4) ? c : (48 + c);
        t32[(8 + r) * TDW + col] = 0xFFFFFFFFu;
    }
    // stage: u8 d -> u16 d^2; 16 z per lane (same y), 8 dword writes
    const uint4* ip = (const uint4*)(in + (size_t)lv * NV + (size_t)x * SXX);
    for (int o = tid; o < SXX / 16; o += 384) {
        uint4 v = ip[o];
        int e = o * 16;
        int y = e / ZD, z = e - y * ZD;
        unsigned int base = (8 + y) * TDW + (8 + z) / 2;
        unsigned int vv[4] = {v.x, v.y, v.z, v.w};
#pragma unroll
        for (int q = 0; q < 4; ++q) {
            unsigned int b0 = vv[q] & 255u, b1 = (vv[q] >> 8) & 255u;
            unsigned int b2 = (vv[q] >> 16) & 255u, b3 = vv[q] >> 24;
            t32[base + 2 * q] = (b0 > 127u ? SENT : b0 * b0) |
                                ((b1 > 127u ? SENT : b1 * b1) << 16);
            t32[base + 2 * q + 1] = (b2 > 127u ? SENT : b2 * b2) |
                                    ((b3 > 127u ? SENT : b3 * b3) << 16);
        }
    }
    __syncthreads();

    {   // ---- phase Y: 4 chunks, same z, i0 = q0 + {0,32,64,96} ----
        const int z0 = tid % 96;
        const int q0 = (tid / 96) * 8;
        float m0[8], m1[8], m2[8], m3[8];
        chunkY(tile, z0, q0,      m0);
        chunkY(tile, z0, q0 + 32, m1);
        chunkY(tile, z0, q0 + 64, m2);
        chunkY(tile, z0, q0 + 96, m3);
        __syncthreads();                 // all window reads done
#pragma unroll
        for (int k = 0; k < 8; ++k) {
            tile[(8 + q0 +      k) * TW2 + 8 + z0] = (unsigned short)fminf(m0[k], (float)SENT);
            tile[(8 + q0 + 32 + k) * TW2 + 8 + z0] = (unsigned short)fminf(m1[k], (float)SENT);
            tile[(8 + q0 + 64 + k) * TW2 + 8 + z0] = (unsigned short)fminf(m2[k], (float)SENT);
            tile[(8 + q0 + 96 + k) * TW2 + 8 + z0] = (unsigned short)fminf(m3[k], (float)SENT);
        }
        __syncthreads();
    }
    {   // ---- phase Z: 4 chunks, same y, i0 = p0 + {0,24,48,72} ----
        const int y0 = tid % 128;
        const int p0 = (tid / 128) * 8;
        float m0[8], m1[8], m2[8], m3[8];
        chunkZ(tile, t32, y0, p0,      m0);
        chunkZ(tile, t32, y0, p0 + 24, m1);
        chunkZ(tile, t32, y0, p0 + 48, m2);
        chunkZ(tile, t32, y0, p0 + 72, m3);
        __syncthreads();
        unsigned int* wp = &t32[(8 + y0) * TDW];
#pragma unroll
        for (int q = 0; q < 4; ++q) {
            wp[(8 + p0) / 2 + q] =
                (unsigned int)fminf(m0[2 * q], (float)SENT) |
                ((unsigned int)fminf(m0[2 * q + 1], (float)SENT) << 16);
            wp[(8 + p0 + 24) / 2 + q] =
                (unsigned int)fminf(m1[2 * q], (float)SENT) |
                ((unsigned int)fminf(m1[2 * q + 1], (float)SENT) << 16);
            wp[(8 + p0 + 48) / 2 + q] =
                (unsigned int)fminf(m2[2 * q], (float)SENT) |
                ((unsigned int)fminf(m2[2 * q + 1], (float)SENT) << 16);
            wp[(8 + p0 + 72) / 2 + q] =
                (unsigned int)fminf(m3[2 * q], (float)SENT) |
                ((unsigned int)fminf(m3[2 * q + 1], (float)SENT) << 16);
        }
        __syncthreads();
    }
    // output: direct dword copy (z-pairs contiguous), uint4 stores
    uint4* op = (uint4*)(out + (size_t)lv * NV + (size_t)x * SXX);
    for (int o = tid; o < SXX / 8; o += 384) {
        int e = o * 8;
        int y = e / ZD, z = e - y * ZD;
        const unsigned int* sp = &t32[(8 + y) * TDW + (8 + z) / 2];
        uint4 v; v.x = sp[0]; v.y = sp[1]; v.z = sp[2]; v.w = sp[3];
        op[o] = v;
    }
}

// ---------------- accum: 4-voxel vectorized (16B/lane), one item/thread ----
__global__ __launch_bounds__(256) void k_accum_batch(const unsigned short* __restrict__ vols,
                                                     const int* __restrict__ gt,
                                                     const float* __restrict__ net,
                                                     const int* __restrict__ flags,
                                                     double* __restrict__ partials,
                                                     int batch0) {
    const int b = batch0 + blockIdx.y;
    const int* g = gt + (size_t)b * NV;
    const float* nb = net + (size_t)b * 4 * NV;
    const unsigned short* vb = vols + (size_t)blockIdx.y * 6 * NV;
    const int fbits = flags[b];

    const int p = blockIdx.x * 256 + threadIdx.x;   // p < NV/4 (grid.x = 1536)
    const int idx = p * 4;

    float4 v0 = *(const float4*)(nb + idx);
    float4 v1 = *(const float4*)(nb + NV + idx);
    float4 v2 = *(const float4*)(nb + 2 * NV + idx);
    float4 v3 = *(const float4*)(nb + 3 * NV + idx);

    float e1[4], e2[4], e3[4], inv[4];
    {
        const float a0[4] = {v0.x, v0.y, v0.z, v0.w};
        const float a1[4] = {v1.x, v1.y, v1.z, v1.w};
        const float a2[4] = {v2.x, v2.y, v2.z, v2.w};
        const float a3[4] = {v3.x, v3.y, v3.z, v3.w};
#pragma unroll
        for (int j = 0; j < 4; ++j) {
            float mx = fmaxf(fmaxf(a0[j], a1[j]), fmaxf(a2[j], a3[j]));
            float x0 = __expf(a0[j] - mx);
            e1[j] = __expf(a1[j] - mx);
            e2[j] = __expf(a2[j] - mx);
            e3[j] = __expf(a3[j] - mx);
            inv[j] = __frcp_rn(x0 + e1[j] + e2[j] + e3[j]);
        }
    }

    const int z4 = idx % ZD;
    const int yy = (idx / ZD) & 127;
    const int xx = idx / SXX;
    int4 gg  = *(const int4*)(g + idx);
    int4 gxm = (xx > 0)   ? *(const int4*)(g + idx - SXX) : gg;
    int4 gxp = (xx < 127) ? *(const int4*)(g + idx + SXX) : gg;
    int4 gym = (yy > 0)   ? *(const int4*)(g + idx - ZD)  : gg;
    int4 gyp = (yy < 127) ? *(const int4*)(g + idx + ZD)  : gg;
    const int gga[4] = {gg.x, gg.y, gg.z, gg.w};
    const int gxma[4] = {gxm.x, gxm.y, gxm.z, gxm.w};
    const int gxpa[4] = {gxp.x, gxp.y, gxp.z, gxp.w};
    const int gyma[4] = {gym.x, gym.y, gym.z, gym.w};
    const int gypa[4] = {gyp.x, gyp.y, gyp.z, gyp.w};
    int gzm[4], gzp[4];
    gzm[0] = (z4 > 0) ? g[idx - 1] : gga[0];
    gzm[1] = gga[0]; gzm[2] = gga[1]; gzm[3] = gga[2];
    gzp[0] = gga[1]; gzp[1] = gga[2]; gzp[2] = gga[3];
    gzp[3] = (z4 < ZD - 4) ? g[idx + 4] : gga[3];

    float acc = 0.0f;
#pragma unroll
    for (int ci = 1; ci <= 3; ++ci) {
        if ((fbits >> ci) & 1) {
            ushort4 dp = *(const ushort4*)(vb + (size_t)(2 * ci - 2) * NV + idx);
            ushort4 dn = *(const ushort4*)(vb + (size_t)(2 * ci - 1) * NV + idx);
            const unsigned short dpa[4] = {dp.x, dp.y, dp.z, dp.w};
            const unsigned short dna[4] = {dn.x, dn.y, dn.z, dn.w};
#pragma unroll
            for (int j = 0; j < 4; ++j) {
                float ec = (ci == 1) ? e1[j] : ((ci == 2) ? e2[j] : e3[j]);
                bool bnd = (gga[j] == ci) &&
                           (gxma[j] != ci || gxpa[j] != ci || gyma[j] != ci ||
                            gypa[j] != ci || gzm[j] != ci || gzp[j] != ci);
                float phi = bnd ? 0.0f
                                : (sqrtf((float)dna[j]) - sqrtf((float)dpa[j]));
                acc += (ec * inv[j]) * phi;
            }
        }
    }
    double ls = (double)acc;

    __shared__ double sd[256];
    sd[threadIdx.x] = ls;
    __syncthreads();
    for (int off = 128; off > 0; off >>= 1) {
        if (threadIdx.x < off) sd[threadIdx.x] += sd[threadIdx.x + off];
        __syncthreads();
    }
    if (threadIdx.x == 0) partials[(size_t)b * 1536 + blockIdx.x] = sd[0];
}

// -------------------------------------------------------------- reduce ----
__global__ void k_reduce(const double* __restrict__ partials, int n,
                         float* __restrict__ out) {
    __shared__ double sd[256];
    double ls = 0.0;
    for (int i = threadIdx.x; i < n; i += 256) ls += partials[i];
    sd[threadIdx.x] = ls;
    __syncthreads();
    for (int off = 128; off > 0; off >>= 1) {
        if (threadIdx.x < off) sd[threadIdx.x] += sd[threadIdx.x + off];
        __syncthreads();
    }
    if (threadIdx.x == 0) out[0] = (float)(sd[0] / 9437184.0);
}

// ---------------------------------------------------------------- launch ----
extern "C" void kernel_launch(void* const* d_in, const int* in_sizes, int n_in,
                              void* d_out, int out_size, void* d_ws, size_t ws_size,
                              hipStream_t stream) {
    const float* net = (const float*)d_in[0];
    const int*   gt  = (const int*)d_in[1];
    float* out = (float*)d_out;
    char* ws = (char*)d_ws;

    const size_t xbufB1 = (size_t)6 * NV;                          // u8,  9.4 MB
    const size_t zbufB1 = (size_t)6 * NV * sizeof(unsigned short); // u16, 18.9 MB
    const size_t tail   = (size_t)3072 * sizeof(double) + 64;

    const int nb = (ws_size >= 2 * (xbufB1 + zbufB1) + tail) ? 2 : 1;

    unsigned char*  xbuf = (unsigned char*)ws;
    unsigned short* zbuf = (unsigned short*)(ws + (size_t)nb * xbufB1);
    double* partials = (double*)(ws + (size_t)nb * (xbufB1 + zbufB1));
    int* flags = (int*)((char*)partials + 3072 * sizeof(double));

    hipLaunchKernelGGL(k_zero_flags, dim3(1), dim3(64), 0, stream, flags);

    for (int b0 = 0; b0 < 2; b0 += nb) {
        hipLaunchKernelGGL(k_scan_x, dim3(SXX / 64, nb), dim3(384), 0, stream,
                           gt, xbuf, flags, b0);
        hipLaunchKernelGGL(k_pass_yz, dim3(XD, 6 * nb), dim3(384), 0, stream,
                           xbuf, zbuf);
        hipLaunchKernelGGL(k_accum_batch, dim3(1536, nb), dim3(256), 0, stream,
                           zbuf, gt, net, flags, partials, b0);
    }
    hipLaunchKernelGGL(k_reduce, dim3(1), dim3(256), 0, stream, partials,
                       3072, out);
}

// Round 12
// 85.339 us; speedup vs baseline: 1.1034x; 1.1034x over previous
//
#include <hip/hip_runtime.h>
#include <math.h>

#define XD 128
#define YD 128
#define ZD 96
#define NV (XD*YD*ZD)      /* 1572864 voxels per volume */
#define SXX (YD*ZD)        /* x-stride = 12288 */
#define SENT 49152         /* sentinel: > any real d^2 (max 41283) */
#define TW2 114            /* u16 cols: 8 pad | 96 z | 10 pad; 57 dw, 57%32=25 */
#define TDW (TW2/2)        /* 57 dwords per row */
#define TROWS 144          /* rows: 8 pad | 128 y | 8 pad */

// ---------------------------------------------------------------- flags ----
__global__ void k_zero_flags(int* flags) {
    if (threadIdx.x < 8) flags[threadIdx.x] = 0;
}

// -------------------------------------------- pass X: binary run-length scan
// 6 waves: wave w6 = 2*c+s owns the (class c+1, sign s) scan for all 64 lines.
// Register-resident scan; in-wave 4x4 byte transpose for the output.
__global__ __launch_bounds__(384) void k_scan_x(const int* __restrict__ gt,
                                                unsigned char* __restrict__ out,
                                                int* __restrict__ flags,
                                                int batch0) {
    const int bb  = blockIdx.y;
    const int myb = batch0 + bb;
    const int tid = threadIdx.x;
    const int l   = tid & 63;
    const int w6  = tid >> 6;            // 0..5
    const int lq0 = blockIdx.x * 64;

    __shared__ unsigned char gtile[64 * 132];
    __shared__ int blkbits;
    if (tid == 0) blkbits = 0;

    int mybits = 0;
    const int* gp = gt + (size_t)myb * NV + lq0 + l;
    for (int j = w6; j < XD; j += 6) {
        int g = gp[(size_t)j * SXX];
        mybits |= 1 << g;
        gtile[l * 132 + j] = (unsigned char)g;
    }
#pragma unroll
    for (int off = 32; off; off >>= 1) mybits |= __shfl_xor(mybits, off);
    __syncthreads();
    if ((tid & 63) == 0) atomicOr(&blkbits, mybits);

    unsigned int D[32];
    {   // thread = (slot w6, line l); slot = 2*c + s; all in registers
        const unsigned int ci = (unsigned int)((w6 >> 1) + 1);
        const int s = w6 & 1;
        unsigned int G[32];
        const unsigned int* grow = (const unsigned int*)gtile + l * 33;
#pragma unroll
        for (int q = 0; q < 32; ++q) G[q] = grow[q];

        int cnt = 200;
#pragma unroll
        for (int q = 0; q < 32; ++q) {
            unsigned int u = G[q], dv = 0;
#pragma unroll
            for (int b = 0; b < 4; ++b) {
                unsigned int gv = (u >> (8 * b)) & 255u;
                bool zero = s ? (gv == ci) : (gv != ci);
                cnt = zero ? 0 : ((cnt < 200) ? cnt + 1 : 200);
                dv |= (unsigned int)cnt << (8 * b);
            }
            D[q] = dv;
        }
        cnt = 200;
#pragma unroll
        for (int q = 31; q >= 0; --q) {
            unsigned int u = G[q], dv = D[q];
#pragma unroll
            for (int b = 3; b >= 0; --b) {
                unsigned int gv = (u >> (8 * b)) & 255u;
                bool zero = s ? (gv == ci) : (gv != ci);
                cnt = zero ? 0 : ((cnt < 200) ? cnt + 1 : 200);
                unsigned int old = (dv >> (8 * b)) & 255u;
                unsigned int nbv = ((unsigned int)cnt < old) ? (unsigned int)cnt : old;
                dv = (dv & ~(255u << (8 * b))) | (nbv << (8 * b));
            }
            D[q] = dv;
        }
    }
    __syncthreads();                     // blkbits complete
    if (tid == 0) atomicOr(&flags[myb], blkbits);

    // in-wave 4x4 byte transpose (groups of 4 lanes = 4 lines) + store
    {
        const int r = l & 3;
        unsigned char* ob = out + (size_t)(bb * 6 + w6) * NV + lq0 + (l & ~3);
#pragma unroll
        for (int q = 0; q < 32; ++q) {
            unsigned int A = D[q];
            unsigned int Bv = (unsigned int)__shfl_xor((int)A, 1);
            unsigned int t = (r & 1)
                ? __builtin_amdgcn_perm(A, Bv, 0x07030501u)
                : __builtin_amdgcn_perm(A, Bv, 0x02060004u);
            unsigned int Cv = (unsigned int)__shfl_xor((int)t, 2);
            unsigned int y = (r & 2)
                ? __builtin_amdgcn_perm(t, Cv, 0x07060302u)
                : __builtin_amdgcn_perm(t, Cv, 0x01000504u);
            *(unsigned int*)(ob + (size_t)(4 * q + r) * SXX) = y;
        }
    }
}

// ------------- EDT fast path: t<=8 on a 32-float register window -----------
// 16 outputs, centers at r[8..23]. Bit-exact vs brute force.
__device__ __forceinline__ bool edt_fast(const float r[32], float m[16]) {
#pragma unroll
    for (int k = 0; k < 16; ++k) m[k] = r[k + 8];
#pragma unroll
    for (int t = 1; t <= 4; ++t) {
        const float t2 = (float)(t * t);
#pragma unroll
        for (int k = 0; k < 16; ++k)
            m[k] = fminf(m[k], fminf(r[k + 8 - t], r[k + 8 + t]) + t2);
    }
    float mm = m[0];
#pragma unroll
    for (int k = 1; k < 16; ++k) mm = fmaxf(mm, m[k]);
    if (__all(mm <= 16.0f)) return true;
#pragma unroll
    for (int t = 5; t <= 8; ++t) {
        const float t2 = (float)(t * t);
#pragma unroll
        for (int k = 0; k < 16; ++k)
            m[k] = fminf(m[k], fminf(r[k + 8 - t], r[k + 8 + t]) + t2);
    }
    mm = m[0];
#pragma unroll
    for (int k = 1; k < 16; ++k) mm = fmaxf(mm, m[k]);
    return __all(mm <= 64.0f) != 0;
}

// ------------- EDT slow path (rare): clamped LDS u16 reads, t>=9 -----------
// p0 points at element j=0 (value at j is p0[j*STRIDE]); valid j in [-8,L+7].
template<int STRIDE, int L>
__device__ void edt_slow(const unsigned short* __restrict__ p0, int i0,
                         float m[16]) {
    int t = 9;
    bool done = false;
    while (!done && t < L) {
        for (int u = 0; u < 4; ++u, ++t) {
            float t2 = (float)(t * t);
#pragma unroll
            for (int k = 0; k < 16; ++k) {
                int jm = i0 + k - t; if (jm < -8) jm = -8;
                int jp = i0 + k + t; if (jp > L + 7) jp = L + 7;
                m[k] = fminf(m[k], fminf((float)p0[jm * STRIDE],
                                         (float)p0[jp * STRIDE]) + t2);
            }
        }
        float mm = m[0];
#pragma unroll
        for (int k = 1; k < 16; ++k) mm = fmaxf(mm, m[k]);
        done = __all(mm <= (float)((t - 1) * (t - 1))) != 0;
    }
}

// ------------- fused Y+Z pass: x-plane in LDS as u16 [y][z] ----------------
// Tile [144 rows = 8|128y|8][114 cols = 8|96z|10] u16, row = 57 dwords
// (57%32=25, coprime; all access patterns bank-conflict-free).
// 768 threads: exactly ONE 16-output chunk per thread per phase (phase Y:
// 96z x 8 chunks; phase Z: 128y x 6 chunks) -> no saved-m across chunks,
// peak live ~60 VGPRs < the (768,6) cap of 85 -> no scratch spill.
__global__ __launch_bounds__(768, 6) void k_pass_yz(const unsigned char* __restrict__ in,
                                                    unsigned short* __restrict__ out) {
    const int lv  = blockIdx.y;          // volume slot
    const int x   = blockIdx.x;
    const int tid = threadIdx.x;
    __shared__ unsigned short tile[TROWS * TW2];
    unsigned int* t32 = (unsigned int*)tile;

    // pad rows (y pads): rows 0..7 and 136..143, full width
    for (int i = tid; i < 16 * TDW; i += 768) {
        int r = i / TDW, c = i - r * TDW;
        int row = (r < 8) ? r : 128 + r;
        t32[row * TDW + c] = 0xFFFFFFFFu;
    }
    // pad cols in data rows: dwords 0..3 (left) and 52..56 (right)
    for (int i = tid; i < 128 * 9; i += 768) {
        int r = i / 9, c = i - r * 9;
        int col = (c < 4) ? c : (48 + c);
        t32[(8 + r) * TDW + col] = 0xFFFFFFFFu;
    }
    // stage: u8 d -> u16 d^2; exactly one uint4 (16 z, same y) per thread
    {
        const uint4* ip = (const uint4*)(in + (size_t)lv * NV + (size_t)x * SXX);
        uint4 v = ip[tid];
        int e = tid * 16;
        int y = e / ZD, z = e - y * ZD;           // z multiple of 16, same y
        unsigned int base = (8 + y) * TDW + (8 + z) / 2;
        unsigned int vv[4] = {v.x, v.y, v.z, v.w};
#pragma unroll
        for (int q = 0; q < 4; ++q) {
            unsigned int b0 = vv[q] & 255u, b1 = (vv[q] >> 8) & 255u;
            unsigned int b2 = (vv[q] >> 16) & 255u, b3 = vv[q] >> 24;
            t32[base + 2 * q] = (b0 > 127u ? SENT : b0 * b0) |
                                ((b1 > 127u ? SENT : b1 * b1) << 16);
            t32[base + 2 * q + 1] = (b2 > 127u ? SENT : b2 * b2) |
                                    ((b3 > 127u ? SENT : b3 * b3) << 16);
        }
    }
    __syncthreads();

    float m[16];
    {   // ---- phase Y (EDT along y; lanes vary z: conflict-free) ----
        const int z0 = tid % 96;
        const int i0 = (tid / 96) * 16;           // 0..7 -> 0..112
        float r[32];
#pragma unroll
        for (int w = 0; w < 32; ++w) r[w] = (float)tile[(i0 + w) * TW2 + 8 + z0];
        if (!edt_fast(r, m)) edt_slow<TW2, YD>(&tile[8 * TW2 + 8 + z0], i0, m);
        __syncthreads();                 // all window reads done
#pragma unroll
        for (int k = 0; k < 16; ++k)
            tile[(8 + i0 + k) * TW2 + 8 + z0] =
                (unsigned short)fminf(m[k], (float)SENT);
        __syncthreads();
    }
    {   // ---- phase Z (EDT along z; rows contiguous, stride-57 coprime) ----
        const int y0 = tid % 128;
        const int i0 = (tid / 128) * 16;          // 0..5 -> 0..80
        float r[32];
        {
            const unsigned int* wp = &t32[(8 + y0) * TDW + i0 / 2];  // u16 col i0
#pragma unroll
            for (int q = 0; q < 16; ++q) {
                unsigned int u = wp[q];
                r[2 * q] = (float)(u & 0xFFFFu);
                r[2 * q + 1] = (float)(u >> 16);
            }
        }
        if (!edt_fast(r, m)) edt_slow<1, ZD>(&tile[(8 + y0) * TW2 + 8], i0, m);
        __syncthreads();
        {
            unsigned int* wp = &t32[(8 + y0) * TDW + (8 + i0) / 2];
#pragma unroll
            for (int q = 0; q < 8; ++q) {
                unsigned int u0 = (unsigned int)fminf(m[2 * q],     (float)SENT);
                unsigned int u1 = (unsigned int)fminf(m[2 * q + 1], (float)SENT);
                wp[q] = u0 | (u1 << 16);
            }
        }
        __syncthreads();
    }
    // output: direct dword copy (z-pairs contiguous), uint4 stores
    uint4* op = (uint4*)(out + (size_t)lv * NV + (size_t)x * SXX);
    for (int o = tid; o < SXX / 8; o += 768) {
        int e = o * 8;
        int y = e / ZD, z = e - y * ZD;           // z multiple of 8, same y
        const unsigned int* sp = &t32[(8 + y) * TDW + (8 + z) / 2];
        uint4 v; v.x = sp[0]; v.y = sp[1]; v.z = sp[2]; v.w = sp[3];
        op[o] = v;
    }
}

// ---------------- accum: 2-voxel vectorized, both batches in one grid ------
__global__ __launch_bounds__(256) void k_accum_batch(const unsigned short* __restrict__ vols,
                                                     const int* __restrict__ gt,
                                                     const float* __restrict__ net,
                                                     const int* __restrict__ flags,
                                                     double* __restrict__ partials,
                                                     int batch0) {
    const int b = batch0 + blockIdx.y;
    double ls = 0.0;
    const int* g = gt + (size_t)b * NV;
    const float* nb = net + (size_t)b * 4 * NV;
    const unsigned short* vb = vols + (size_t)blockIdx.y * 6 * NV;
    const int fbits = flags[b];
    const int NP = NV / 2;
    for (int p = blockIdx.x * 256 + threadIdx.x; p < NP; p += 1024 * 256) {
        const int idx = p * 2;
        float2 v0 = *(const float2*)(nb + idx);
        float2 v1 = *(const float2*)(nb + NV + idx);
        float2 v2 = *(const float2*)(nb + 2 * NV + idx);
        float2 v3 = *(const float2*)(nb + 3 * NV + idx);

        float mxa = fmaxf(fmaxf(v0.x, v1.x), fmaxf(v2.x, v3.x));
        float mxb = fmaxf(fmaxf(v0.y, v1.y), fmaxf(v2.y, v3.y));
        float e1a = __expf(v1.x - mxa), e2a = __expf(v2.x - mxa), e3a = __expf(v3.x - mxa);
        float e1b = __expf(v1.y - mxb), e2b = __expf(v2.y - mxb), e3b = __expf(v3.y - mxb);
        float sa = __expf(v0.x - mxa) + e1a + e2a + e3a;
        float sb = __expf(v0.y - mxb) + e1b + e2b + e3b;
        float ia = __frcp_rn(sa);
        float ib = __frcp_rn(sb);

        const int zp = p % 48;              // voxel z = 2*zp, 2*zp+1
        const int yy = (p / 48) & 127;
        const int xx = p / 6144;
        int2 gg  = *(const int2*)(g + idx);
        int2 gxm = (xx > 0)   ? *(const int2*)(g + idx - SXX) : gg;
        int2 gxp = (xx < 127) ? *(const int2*)(g + idx + SXX) : gg;
        int2 gym = (yy > 0)   ? *(const int2*)(g + idx - ZD)  : gg;
        int2 gyp = (yy < 127) ? *(const int2*)(g + idx + ZD)  : gg;
        int zm0 = (zp > 0)  ? g[idx - 1] : gg.x;
        int zp1 = (zp < 47) ? g[idx + 2] : gg.y;

        float acc = 0.0f;
#pragma unroll
        for (int ci = 1; ci <= 3; ++ci) {
            if ((fbits >> ci) & 1) {
                ushort2 dp = *(const ushort2*)(vb + (size_t)(2 * ci - 2) * NV + idx);
                ushort2 dn = *(const ushort2*)(vb + (size_t)(2 * ci - 1) * NV + idx);
                float ea = (ci == 1) ? e1a : ((ci == 2) ? e2a : e3a);
                float eb = (ci == 1) ? e1b : ((ci == 2) ? e2b : e3b);
                bool bndA = (gg.x == ci) &&
                            (gxm.x != ci || gxp.x != ci || gym.x != ci ||
                             gyp.x != ci || zm0 != ci || gg.y != ci);
                bool bndB = (gg.y == ci) &&
                            (gxm.y != ci || gxp.y != ci || gym.y != ci ||
                             gyp.y != ci || gg.x != ci || zp1 != ci);
                float phiA = bndA ? 0.0f : (sqrtf((float)dn.x) - sqrtf((float)dp.x));
                float phiB = bndB ? 0.0f : (sqrtf((float)dn.y) - sqrtf((float)dp.y));
                acc += (ea * ia) * phiA + (eb * ib) * phiB;
            }
        }
        ls += (double)acc;
    }
    __shared__ double sd[256];
    sd[threadIdx.x] = ls;
    __syncthreads();
    for (int off = 128; off > 0; off >>= 1) {
        if (threadIdx.x < off) sd[threadIdx.x] += sd[threadIdx.x + off];
        __syncthreads();
    }
    if (threadIdx.x == 0) partials[(size_t)b * 1024 + blockIdx.x] = sd[0];
}

// -------------------------------------------------------------- reduce ----
__global__ void k_reduce(const double* __restrict__ partials, int n,
                         float* __restrict__ out) {
    __shared__ double sd[256];
    double ls = 0.0;
    for (int i = threadIdx.x; i < n; i += 256) ls += partials[i];
    sd[threadIdx.x] = ls;
    __syncthreads();
    for (int off = 128; off > 0; off >>= 1) {
        if (threadIdx.x < off) sd[threadIdx.x] += sd[threadIdx.x + off];
        __syncthreads();
    }
    if (threadIdx.x == 0) out[0] = (float)(sd[0] / 9437184.0);
}

// ---------------------------------------------------------------- launch ----
extern "C" void kernel_launch(void* const* d_in, const int* in_sizes, int n_in,
                              void* d_out, int out_size, void* d_ws, size_t ws_size,
                              hipStream_t stream) {
    const float* net = (const float*)d_in[0];
    const int*   gt  = (const int*)d_in[1];
    float* out = (float*)d_out;
    char* ws = (char*)d_ws;

    const size_t xbufB1 = (size_t)6 * NV;                          // u8,  9.4 MB
    const size_t zbufB1 = (size_t)6 * NV * sizeof(unsigned short); // u16, 18.9 MB
    const size_t tail   = (size_t)2048 * sizeof(double) + 64;

    const int nb = (ws_size >= 2 * (xbufB1 + zbufB1) + tail) ? 2 : 1;

    unsigned char*  xbuf = (unsigned char*)ws;
    unsigned short* zbuf = (unsigned short*)(ws + (size_t)nb * xbufB1);
    double* partials = (double*)(ws + (size_t)nb * (xbufB1 + zbufB1));
    int* flags = (int*)((char*)partials + 2048 * sizeof(double));

    hipLaunchKernelGGL(k_zero_flags, dim3(1), dim3(64), 0, stream, flags);

    for (int b0 = 0; b0 < 2; b0 += nb) {
        hipLaunchKernelGGL(k_scan_x, dim3(SXX / 64, nb), dim3(384), 0, stream,
                           gt, xbuf, flags, b0);
        hipLaunchKernelGGL(k_pass_yz, dim3(XD, 6 * nb), dim3(768), 0, stream,
                           xbuf, zbuf);
        hipLaunchKernelGGL(k_accum_batch, dim3(1024, nb), dim3(256), 0, stream,
                           zbuf, gt, net, flags, partials, b0);
    }
    hipLaunchKernelGGL(k_reduce, dim3(1), dim3(256), 0, stream, partials,
                       2048, out);
}

// Round 13
// 81.955 us; speedup vs baseline: 1.1490x; 1.0413x over previous
//
#include <hip/hip_runtime.h>
#include <math.h>

#define XD 128
#define YD 128
#define ZD 96
#define NV (XD*YD*ZD)      /* 1572864 voxels per volume */
#define SXX (YD*ZD)        /* x-stride = 12288 */
#define SENT 49152         /* sentinel: > any real d^2 (max 41283) */
#define TW2 114            /* u16 cols: 8 pad | 96 z | 10 pad; 57 dw, 57%32=25 */
#define TDW (TW2/2)        /* 57 dwords per row */
#define TROWS 144          /* rows: 8 pad | 128 y | 8 pad */

// ---------------------------------------------------------------- flags ----
__global__ void k_zero_flags(int* flags) {
    if (threadIdx.x < 8) flags[threadIdx.x] = 0;
}

// -------------------------------------------- pass X: binary run-length scan
// 6 waves: wave w6 = 2*c+s owns the (class c+1, sign s) scan for all 64 lines.
// Register-resident scan; in-wave 4x4 byte transpose for the output.
__global__ __launch_bounds__(384) void k_scan_x(const int* __restrict__ gt,
                                                unsigned char* __restrict__ out,
                                                int* __restrict__ flags,
                                                int batch0) {
    const int bb  = blockIdx.y;
    const int myb = batch0 + bb;
    const int tid = threadIdx.x;
    const int l   = tid & 63;
    const int w6  = tid >> 6;            // 0..5
    const int lq0 = blockIdx.x * 64;

    __shared__ unsigned char gtile[64 * 132];
    __shared__ int blkbits;
    if (tid == 0) blkbits = 0;

    int mybits = 0;
    const int* gp = gt + (size_t)myb * NV + lq0 + l;
    for (int j = w6; j < XD; j += 6) {
        int g = gp[(size_t)j * SXX];
        mybits |= 1 << g;
        gtile[l * 132 + j] = (unsigned char)g;
    }
#pragma unroll
    for (int off = 32; off; off >>= 1) mybits |= __shfl_xor(mybits, off);
    __syncthreads();
    if ((tid & 63) == 0) atomicOr(&blkbits, mybits);

    unsigned int D[32];
    {   // thread = (slot w6, line l); slot = 2*c + s; all in registers
        const unsigned int ci = (unsigned int)((w6 >> 1) + 1);
        const int s = w6 & 1;
        unsigned int G[32];
        const unsigned int* grow = (const unsigned int*)gtile + l * 33;
#pragma unroll
        for (int q = 0; q < 32; ++q) G[q] = grow[q];

        int cnt = 200;
#pragma unroll
        for (int q = 0; q < 32; ++q) {
            unsigned int u = G[q], dv = 0;
#pragma unroll
            for (int b = 0; b < 4; ++b) {
                unsigned int gv = (u >> (8 * b)) & 255u;
                bool zero = s ? (gv == ci) : (gv != ci);
                cnt = zero ? 0 : ((cnt < 200) ? cnt + 1 : 200);
                dv |= (unsigned int)cnt << (8 * b);
            }
            D[q] = dv;
        }
        cnt = 200;
#pragma unroll
        for (int q = 31; q >= 0; --q) {
            unsigned int u = G[q], dv = D[q];
#pragma unroll
            for (int b = 3; b >= 0; --b) {
                unsigned int gv = (u >> (8 * b)) & 255u;
                bool zero = s ? (gv == ci) : (gv != ci);
                cnt = zero ? 0 : ((cnt < 200) ? cnt + 1 : 200);
                unsigned int old = (dv >> (8 * b)) & 255u;
                unsigned int nbv = ((unsigned int)cnt < old) ? (unsigned int)cnt : old;
                dv = (dv & ~(255u << (8 * b))) | (nbv << (8 * b));
            }
            D[q] = dv;
        }
    }
    __syncthreads();                     // blkbits complete
    if (tid == 0) atomicOr(&flags[myb], blkbits);

    // in-wave 4x4 byte transpose (groups of 4 lanes = 4 lines) + store
    {
        const int r = l & 3;
        unsigned char* ob = out + (size_t)(bb * 6 + w6) * NV + lq0 + (l & ~3);
#pragma unroll
        for (int q = 0; q < 32; ++q) {
            unsigned int A = D[q];
            unsigned int Bv = (unsigned int)__shfl_xor((int)A, 1);
            unsigned int t = (r & 1)
                ? __builtin_amdgcn_perm(A, Bv, 0x07030501u)
                : __builtin_amdgcn_perm(A, Bv, 0x02060004u);
            unsigned int Cv = (unsigned int)__shfl_xor((int)t, 2);
            unsigned int y = (r & 2)
                ? __builtin_amdgcn_perm(t, Cv, 0x07060302u)
                : __builtin_amdgcn_perm(t, Cv, 0x01000504u);
            *(unsigned int*)(ob + (size_t)(4 * q + r) * SXX) = y;
        }
    }
}

// ------------- EDT fast path: t<=8 on a 32-float register window -----------
// 16 outputs, centers at r[8..23]. Bit-exact vs brute force.
__device__ __forceinline__ bool edt_fast(const float r[32], float m[16]) {
#pragma unroll
    for (int k = 0; k < 16; ++k) m[k] = r[k + 8];
#pragma unroll
    for (int t = 1; t <= 4; ++t) {
        const float t2 = (float)(t * t);
#pragma unroll
        for (int k = 0; k < 16; ++k)
            m[k] = fminf(m[k], fminf(r[k + 8 - t], r[k + 8 + t]) + t2);
    }
    float mm = m[0];
#pragma unroll
    for (int k = 1; k < 16; ++k) mm = fmaxf(mm, m[k]);
    if (__all(mm <= 16.0f)) return true;
#pragma unroll
    for (int t = 5; t <= 8; ++t) {
        const float t2 = (float)(t * t);
#pragma unroll
        for (int k = 0; k < 16; ++k)
            m[k] = fminf(m[k], fminf(r[k + 8 - t], r[k + 8 + t]) + t2);
    }
    mm = m[0];
#pragma unroll
    for (int k = 1; k < 16; ++k) mm = fmaxf(mm, m[k]);
    return __all(mm <= 64.0f) != 0;
}

// ------------- EDT slow path (rare): clamped LDS u16 reads, t>=9 -----------
// p0 points at element j=0 (value at j is p0[j*STRIDE]); valid j in [-8,L+7].
template<int STRIDE, int L>
__device__ void edt_slow(const unsigned short* __restrict__ p0, int i0,
                         float m[16]) {
    int t = 9;
    bool done = false;
    while (!done && t < L) {
        for (int u = 0; u < 4; ++u, ++t) {
            float t2 = (float)(t * t);
#pragma unroll
            for (int k = 0; k < 16; ++k) {
                int jm = i0 + k - t; if (jm < -8) jm = -8;
                int jp = i0 + k + t; if (jp > L + 7) jp = L + 7;
                m[k] = fminf(m[k], fminf((float)p0[jm * STRIDE],
                                         (float)p0[jp * STRIDE]) + t2);
            }
        }
        float mm = m[0];
#pragma unroll
        for (int k = 1; k < 16; ++k) mm = fmaxf(mm, m[k]);
        done = __all(mm <= (float)((t - 1) * (t - 1))) != 0;
    }
}

// ------------- fused Y+Z pass: x-plane in LDS as u16 [y][z] ----------------
// Tile [144 rows = 8|128y|8][114 cols = 8|96z|10] u16, row = 57 dwords
// (57%32=25, coprime; all access patterns bank-conflict-free).
// 768 threads: exactly ONE 16-output chunk per thread per phase.
__global__ __launch_bounds__(768, 6) void k_pass_yz(const unsigned char* __restrict__ in,
                                                    unsigned short* __restrict__ out) {
    const int lv  = blockIdx.y;          // volume slot
    const int x   = blockIdx.x;
    const int tid = threadIdx.x;
    __shared__ unsigned short tile[TROWS * TW2];
    unsigned int* t32 = (unsigned int*)tile;

    // pad rows (y pads): rows 0..7 and 136..143, full width
    for (int i = tid; i < 16 * TDW; i += 768) {
        int r = i / TDW, c = i - r * TDW;
        int row = (r < 8) ? r : 128 + r;
        t32[row * TDW + c] = 0xFFFFFFFFu;
    }
    // pad cols in data rows: dwords 0..3 (left) and 52..56 (right)
    for (int i = tid; i < 128 * 9; i += 768) {
        int r = i / 9, c = i - r * 9;
        int col = (c < 4) ? c : (48 + c);
        t32[(8 + r) * TDW + col] = 0xFFFFFFFFu;
    }
    // stage: u8 d -> u16 d^2; exactly one uint4 (16 z, same y) per thread
    {
        const uint4* ip = (const uint4*)(in + (size_t)lv * NV + (size_t)x * SXX);
        uint4 v = ip[tid];
        int e = tid * 16;
        int y = e / ZD, z = e - y * ZD;           // z multiple of 16, same y
        unsigned int base = (8 + y) * TDW + (8 + z) / 2;
        unsigned int vv[4] = {v.x, v.y, v.z, v.w};
#pragma unroll
        for (int q = 0; q < 4; ++q) {
            unsigned int b0 = vv[q] & 255u, b1 = (vv[q] >> 8) & 255u;
            unsigned int b2 = (vv[q] >> 16) & 255u, b3 = vv[q] >> 24;
            t32[base + 2 * q] = (b0 > 127u ? SENT : b0 * b0) |
                                ((b1 > 127u ? SENT : b1 * b1) << 16);
            t32[base + 2 * q + 1] = (b2 > 127u ? SENT : b2 * b2) |
                                    ((b3 > 127u ? SENT : b3 * b3) << 16);
        }
    }
    __syncthreads();

    float m[16];
    {   // ---- phase Y (EDT along y; lanes vary z: conflict-free) ----
        const int z0 = tid % 96;
        const int i0 = (tid / 96) * 16;           // 0..7 -> 0..112
        float r[32];
#pragma unroll
        for (int w = 0; w < 32; ++w) r[w] = (float)tile[(i0 + w) * TW2 + 8 + z0];
        if (!edt_fast(r, m)) edt_slow<TW2, YD>(&tile[8 * TW2 + 8 + z0], i0, m);
        __syncthreads();                 // all window reads done
#pragma unroll
        for (int k = 0; k < 16; ++k)
            tile[(8 + i0 + k) * TW2 + 8 + z0] =
                (unsigned short)fminf(m[k], (float)SENT);
        __syncthreads();
    }
    {   // ---- phase Z (EDT along z; rows contiguous, stride-57 coprime) ----
        const int y0 = tid % 128;
        const int i0 = (tid / 128) * 16;          // 0..5 -> 0..80
        float r[32];
        {
            const unsigned int* wp = &t32[(8 + y0) * TDW + i0 / 2];  // u16 col i0
#pragma unroll
            for (int q = 0; q < 16; ++q) {
                unsigned int u = wp[q];
                r[2 * q] = (float)(u & 0xFFFFu);
                r[2 * q + 1] = (float)(u >> 16);
            }
        }
        if (!edt_fast(r, m)) edt_slow<1, ZD>(&tile[(8 + y0) * TW2 + 8], i0, m);
        __syncthreads();
        {
            unsigned int* wp = &t32[(8 + y0) * TDW + (8 + i0) / 2];
#pragma unroll
            for (int q = 0; q < 8; ++q) {
                unsigned int u0 = (unsigned int)fminf(m[2 * q],     (float)SENT);
                unsigned int u1 = (unsigned int)fminf(m[2 * q + 1], (float)SENT);
                wp[q] = u0 | (u1 << 16);
            }
        }
        __syncthreads();
    }
    // output: direct dword copy (z-pairs contiguous), uint4 stores
    uint4* op = (uint4*)(out + (size_t)lv * NV + (size_t)x * SXX);
    for (int o = tid; o < SXX / 8; o += 768) {
        int e = o * 8;
        int y = e / ZD, z = e - y * ZD;           // z multiple of 8, same y
        const unsigned int* sp = &t32[(8 + y) * TDW + (8 + z) / 2];
        uint4 v; v.x = sp[0]; v.y = sp[1]; v.z = sp[2]; v.w = sp[3];
        op[o] = v;
    }
}

// ---------------- accum: boundary via dp==1 (no gt reads at all) -----------
// inner_boundary(onehot) == (posdis^2 == 1): a foreground voxel has an
// in-volume background face-neighbor iff its EDT distance is exactly 1;
// background voxels have dp=0. Edge replication agrees (border voxel with
// all-foreground in-volume neighbors has dp^2 >= 2). Exact equivalence.
__global__ __launch_bounds__(256) void k_accum_batch(const unsigned short* __restrict__ vols,
                                                     const float* __restrict__ net,
                                                     const int* __restrict__ flags,
                                                     double* __restrict__ partials,
                                                     int batch0) {
    const int b = batch0 + blockIdx.y;
    double ls = 0.0;
    const float* nb = net + (size_t)b * 4 * NV;
    const unsigned short* vb = vols + (size_t)blockIdx.y * 6 * NV;
    const int fbits = flags[b];
    const int NP = NV / 2;
    for (int p = blockIdx.x * 256 + threadIdx.x; p < NP; p += 1024 * 256) {
        const int idx = p * 2;
        float2 v0 = *(const float2*)(nb + idx);
        float2 v1 = *(const float2*)(nb + NV + idx);
        float2 v2 = *(const float2*)(nb + 2 * NV + idx);
        float2 v3 = *(const float2*)(nb + 3 * NV + idx);

        float mxa = fmaxf(fmaxf(v0.x, v1.x), fmaxf(v2.x, v3.x));
        float mxb = fmaxf(fmaxf(v0.y, v1.y), fmaxf(v2.y, v3.y));
        float e1a = __expf(v1.x - mxa), e2a = __expf(v2.x - mxa), e3a = __expf(v3.x - mxa);
        float e1b = __expf(v1.y - mxb), e2b = __expf(v2.y - mxb), e3b = __expf(v3.y - mxb);
        float sa = __expf(v0.x - mxa) + e1a + e2a + e3a;
        float sb = __expf(v0.y - mxb) + e1b + e2b + e3b;
        float ia = __frcp_rn(sa);
        float ib = __frcp_rn(sb);

        float acc = 0.0f;
#pragma unroll
        for (int ci = 1; ci <= 3; ++ci) {
            if ((fbits >> ci) & 1) {
                ushort2 dp = *(const ushort2*)(vb + (size_t)(2 * ci - 2) * NV + idx);
                ushort2 dn = *(const ushort2*)(vb + (size_t)(2 * ci - 1) * NV + idx);
                float ea = (ci == 1) ? e1a : ((ci == 2) ? e2a : e3a);
                float eb = (ci == 1) ? e1b : ((ci == 2) ? e2b : e3b);
                float phiA = (dp.x == 1) ? 0.0f
                           : (sqrtf((float)dn.x) - sqrtf((float)dp.x));
                float phiB = (dp.y == 1) ? 0.0f
                           : (sqrtf((float)dn.y) - sqrtf((float)dp.y));
                acc += (ea * ia) * phiA + (eb * ib) * phiB;
            }
        }
        ls += (double)acc;
    }
    __shared__ double sd[256];
    sd[threadIdx.x] = ls;
    __syncthreads();
    for (int off = 128; off > 0; off >>= 1) {
        if (threadIdx.x < off) sd[threadIdx.x] += sd[threadIdx.x + off];
        __syncthreads();
    }
    if (threadIdx.x == 0) partials[(size_t)b * 1024 + blockIdx.x] = sd[0];
}

// -------------------------------------------------------------- reduce ----
__global__ void k_reduce(const double* __restrict__ partials, int n,
                         float* __restrict__ out) {
    __shared__ double sd[256];
    double ls = 0.0;
    for (int i = threadIdx.x; i < n; i += 256) ls += partials[i];
    sd[threadIdx.x] = ls;
    __syncthreads();
    for (int off = 128; off > 0; off >>= 1) {
        if (threadIdx.x < off) sd[threadIdx.x] += sd[threadIdx.x + off];
        __syncthreads();
    }
    if (threadIdx.x == 0) out[0] = (float)(sd[0] / 9437184.0);
}

// ---------------------------------------------------------------- launch ----
extern "C" void kernel_launch(void* const* d_in, const int* in_sizes, int n_in,
                              void* d_out, int out_size, void* d_ws, size_t ws_size,
                              hipStream_t stream) {
    const float* net = (const float*)d_in[0];
    const int*   gt  = (const int*)d_in[1];
    float* out = (float*)d_out;
    char* ws = (char*)d_ws;

    const size_t xbufB1 = (size_t)6 * NV;                          // u8,  9.4 MB
    const size_t zbufB1 = (size_t)6 * NV * sizeof(unsigned short); // u16, 18.9 MB
    const size_t tail   = (size_t)2048 * sizeof(double) + 64;

    const int nb = (ws_size >= 2 * (xbufB1 + zbufB1) + tail) ? 2 : 1;

    unsigned char*  xbuf = (unsigned char*)ws;
    unsigned short* zbuf = (unsigned short*)(ws + (size_t)nb * xbufB1);
    double* partials = (double*)(ws + (size_t)nb * (xbufB1 + zbufB1));
    int* flags = (int*)((char*)partials + 2048 * sizeof(double));

    hipLaunchKernelGGL(k_zero_flags, dim3(1), dim3(64), 0, stream, flags);

    for (int b0 = 0; b0 < 2; b0 += nb) {
        hipLaunchKernelGGL(k_scan_x, dim3(SXX / 64, nb), dim3(384), 0, stream,
                           gt, xbuf, flags, b0);
        hipLaunchKernelGGL(k_pass_yz, dim3(XD, 6 * nb), dim3(768), 0, stream,
                           xbuf, zbuf);
        hipLaunchKernelGGL(k_accum_batch, dim3(1024, nb), dim3(256), 0, stream,
                           zbuf, net, flags, partials, b0);
    }
    hipLaunchKernelGGL(k_reduce, dim3(1), dim3(256), 0, stream, partials,
                       2048, out);
}

// Round 14
// 80.025 us; speedup vs baseline: 1.1767x; 1.0241x over previous
//
#include <hip/hip_runtime.h>
#include <hip/hip_fp16.h>
#include <math.h>

#define XD 128
#define YD 128
#define ZD 96
#define NV (XD*YD*ZD)      /* 1572864 voxels per volume */
#define SXX (YD*ZD)        /* x-stride = 12288 */
#define SENT 49152         /* sentinel: > any real d^2 (max 41283) */
#define TW2 114            /* u16 cols: 8 pad | 96 z | 10 pad; 57 dw, 57%32=25 */
#define TDW (TW2/2)        /* 57 dwords per row */
#define TROWS 144          /* rows: 8 pad | 128 y | 8 pad */

// ---------------------------------------------------------------- flags ----
__global__ void k_zero_flags(int* flags) {
    if (threadIdx.x < 8) flags[threadIdx.x] = 0;
}

// -------------------------------------------- pass X: binary run-length scan
// 6 waves: wave w6 = 2*c+s owns the (class c+1, sign s) scan for all 64 lines.
// Register-resident scan; in-wave 4x4 byte transpose for the output.
__global__ __launch_bounds__(384) void k_scan_x(const int* __restrict__ gt,
                                                unsigned char* __restrict__ out,
                                                int* __restrict__ flags,
                                                int batch0) {
    const int bb  = blockIdx.y;
    const int myb = batch0 + bb;
    const int tid = threadIdx.x;
    const int l   = tid & 63;
    const int w6  = tid >> 6;            // 0..5
    const int lq0 = blockIdx.x * 64;

    __shared__ unsigned char gtile[64 * 132];
    __shared__ int blkbits;
    if (tid == 0) blkbits = 0;

    int mybits = 0;
    const int* gp = gt + (size_t)myb * NV + lq0 + l;
    for (int j = w6; j < XD; j += 6) {
        int g = gp[(size_t)j * SXX];
        mybits |= 1 << g;
        gtile[l * 132 + j] = (unsigned char)g;
    }
#pragma unroll
    for (int off = 32; off; off >>= 1) mybits |= __shfl_xor(mybits, off);
    __syncthreads();
    if ((tid & 63) == 0) atomicOr(&blkbits, mybits);

    unsigned int D[32];
    {   // thread = (slot w6, line l); slot = 2*c + s; all in registers
        const unsigned int ci = (unsigned int)((w6 >> 1) + 1);
        const int s = w6 & 1;
        unsigned int G[32];
        const unsigned int* grow = (const unsigned int*)gtile + l * 33;
#pragma unroll
        for (int q = 0; q < 32; ++q) G[q] = grow[q];

        int cnt = 200;
#pragma unroll
        for (int q = 0; q < 32; ++q) {
            unsigned int u = G[q], dv = 0;
#pragma unroll
            for (int b = 0; b < 4; ++b) {
                unsigned int gv = (u >> (8 * b)) & 255u;
                bool zero = s ? (gv == ci) : (gv != ci);
                cnt = zero ? 0 : ((cnt < 200) ? cnt + 1 : 200);
                dv |= (unsigned int)cnt << (8 * b);
            }
            D[q] = dv;
        }
        cnt = 200;
#pragma unroll
        for (int q = 31; q >= 0; --q) {
            unsigned int u = G[q], dv = D[q];
#pragma unroll
            for (int b = 3; b >= 0; --b) {
                unsigned int gv = (u >> (8 * b)) & 255u;
                bool zero = s ? (gv == ci) : (gv != ci);
                cnt = zero ? 0 : ((cnt < 200) ? cnt + 1 : 200);
                unsigned int old = (dv >> (8 * b)) & 255u;
                unsigned int nbv = ((unsigned int)cnt < old) ? (unsigned int)cnt : old;
                dv = (dv & ~(255u << (8 * b))) | (nbv << (8 * b));
            }
            D[q] = dv;
        }
    }
    __syncthreads();                     // blkbits complete
    if (tid == 0) atomicOr(&flags[myb], blkbits);

    // in-wave 4x4 byte transpose (groups of 4 lanes = 4 lines) + store
    {
        const int r = l & 3;
        unsigned char* ob = out + (size_t)(bb * 6 + w6) * NV + lq0 + (l & ~3);
#pragma unroll
        for (int q = 0; q < 32; ++q) {
            unsigned int A = D[q];
            unsigned int Bv = (unsigned int)__shfl_xor((int)A, 1);
            unsigned int t = (r & 1)
                ? __builtin_amdgcn_perm(A, Bv, 0x07030501u)
                : __builtin_amdgcn_perm(A, Bv, 0x02060004u);
            unsigned int Cv = (unsigned int)__shfl_xor((int)t, 2);
            unsigned int y = (r & 2)
                ? __builtin_amdgcn_perm(t, Cv, 0x07060302u)
                : __builtin_amdgcn_perm(t, Cv, 0x01000504u);
            *(unsigned int*)(ob + (size_t)(4 * q + r) * SXX) = y;
        }
    }
}

// ---------------- probs: softmax pre-pass, f16 output per class ------------
// p computed with the exact ops R13's accum used (mx, __expf, __frcp_rn);
// only the f16 store rounds (|rel| <= 2.4e-4, final-mean error << threshold).
__global__ __launch_bounds__(256) void k_prob(const float* __restrict__ net,
                                              __half2* __restrict__ probs,
                                              int batch0) {
    const int b = batch0 + blockIdx.y;
    const float* nb = net + (size_t)b * 4 * NV;
    const int p = blockIdx.x * 256 + threadIdx.x;   // < NV/2 (grid.x = 3072)
    const int idx = p * 2;
    float2 v0 = *(const float2*)(nb + idx);
    float2 v1 = *(const float2*)(nb + NV + idx);
    float2 v2 = *(const float2*)(nb + 2 * NV + idx);
    float2 v3 = *(const float2*)(nb + 3 * NV + idx);

    float mxa = fmaxf(fmaxf(v0.x, v1.x), fmaxf(v2.x, v3.x));
    float mxb = fmaxf(fmaxf(v0.y, v1.y), fmaxf(v2.y, v3.y));
    float e1a = __expf(v1.x - mxa), e2a = __expf(v2.x - mxa), e3a = __expf(v3.x - mxa);
    float e1b = __expf(v1.y - mxb), e2b = __expf(v2.y - mxb), e3b = __expf(v3.y - mxb);
    float sa = __expf(v0.x - mxa) + e1a + e2a + e3a;
    float sb = __expf(v0.y - mxb) + e1b + e2b + e3b;
    float ia = __frcp_rn(sa), ib = __frcp_rn(sb);

    const size_t h2 = (size_t)p;
    probs[(size_t)(b * 3 + 0) * (NV / 2) + h2] = __floats2half2_rn(e1a * ia, e1b * ib);
    probs[(size_t)(b * 3 + 1) * (NV / 2) + h2] = __floats2half2_rn(e2a * ia, e2b * ib);
    probs[(size_t)(b * 3 + 2) * (NV / 2) + h2] = __floats2half2_rn(e3a * ia, e3b * ib);
}

// ------------- EDT fast path: t<=8 on a 32-float register window -----------
__device__ __forceinline__ bool edt_fast(const float r[32], float m[16]) {
#pragma unroll
    for (int k = 0; k < 16; ++k) m[k] = r[k + 8];
#pragma unroll
    for (int t = 1; t <= 4; ++t) {
        const float t2 = (float)(t * t);
#pragma unroll
        for (int k = 0; k < 16; ++k)
            m[k] = fminf(m[k], fminf(r[k + 8 - t], r[k + 8 + t]) + t2);
    }
    float mm = m[0];
#pragma unroll
    for (int k = 1; k < 16; ++k) mm = fmaxf(mm, m[k]);
    if (__all(mm <= 16.0f)) return true;
#pragma unroll
    for (int t = 5; t <= 8; ++t) {
        const float t2 = (float)(t * t);
#pragma unroll
        for (int k = 0; k < 16; ++k)
            m[k] = fminf(m[k], fminf(r[k + 8 - t], r[k + 8 + t]) + t2);
    }
    mm = m[0];
#pragma unroll
    for (int k = 1; k < 16; ++k) mm = fmaxf(mm, m[k]);
    return __all(mm <= 64.0f) != 0;
}

// ------------- EDT slow path (rare): clamped LDS u16 reads, t>=9 -----------
template<int STRIDE, int L>
__device__ void edt_slow(const unsigned short* __restrict__ p0, int i0,
                         float m[16]) {
    int t = 9;
    bool done = false;
    while (!done && t < L) {
        for (int u = 0; u < 4; ++u, ++t) {
            float t2 = (float)(t * t);
#pragma unroll
            for (int k = 0; k < 16; ++k) {
                int jm = i0 + k - t; if (jm < -8) jm = -8;
                int jp = i0 + k + t; if (jp > L + 7) jp = L + 7;
                m[k] = fminf(m[k], fminf((float)p0[jm * STRIDE],
                                         (float)p0[jp * STRIDE]) + t2);
            }
        }
        float mm = m[0];
#pragma unroll
        for (int k = 1; k < 16; ++k) mm = fmaxf(mm, m[k]);
        done = __all(mm <= (float)((t - 1) * (t - 1))) != 0;
    }
}

// ------ fused Y+Z EDT + loss accumulation: one (x, class, batch) block -----
// Single u16 [y][z] tile (32.8 KB; pads survive re-staging). Sequence:
// stage pos -> EDT -> pack dp^2 into 8 VGPRs -> re-stage neg in SAME tile ->
// EDT -> phi = (dp==1)?0:sqrt(dn)-sqrt(dp) -> p*phi block-reduce.
// EDT volumes never touch HBM; WRITE = 8 bytes/block.
__global__ __launch_bounds__(768, 6) void k_yz_acc(const unsigned char* __restrict__ in,
                                                   const __half2* __restrict__ probs,
                                                   const int* __restrict__ flags,
                                                   double* __restrict__ partials,
                                                   int batch0) {
    const int x   = blockIdx.x;
    const int bbl = blockIdx.y / 3;      // local batch (xbuf slot group)
    const int c   = blockIdx.y % 3;      // class-1
    const int b   = batch0 + bbl;        // global batch
    const int tid = threadIdx.x;
    const int pidx = (b * 3 + c) * XD + x;

    __shared__ unsigned short tile[TROWS * TW2];
    __shared__ double sd[768];
    unsigned int* t32 = (unsigned int*)tile;

    if (((flags[b] >> (c + 1)) & 1) == 0) {
        if (tid == 0) partials[pidx] = 0.0;
        return;
    }

    // pads (once; EDT write-backs and re-staging touch only data cells)
    for (int i = tid; i < 16 * TDW; i += 768) {
        int r = i / TDW, cc = i - r * TDW;
        int row = (r < 8) ? r : 128 + r;
        t32[row * TDW + cc] = 0xFFFFFFFFu;
    }
    for (int i = tid; i < 128 * 9; i += 768) {
        int r = i / 9, cc = i - r * 9;
        int col = (cc < 4) ? cc : (48 + cc);
        t32[(8 + r) * TDW + col] = 0xFFFFFFFFu;
    }

    const int z0 = tid % 96;  const int iY = (tid / 96) * 16;
    const int y0 = tid % 128; const int iZ = (tid / 128) * 16;
    const int e  = tid * 16;
    const int sy = e / ZD, sz = e - sy * ZD;
    const unsigned int sbase = (8 + sy) * TDW + (8 + sz) / 2;

    float m[16];
    unsigned int dpp[8];

    // ================= pos plane (slot 2c) =================
    {
        const uint4* ip = (const uint4*)(in + (size_t)(bbl * 6 + 2 * c) * NV +
                                         (size_t)x * SXX);
        uint4 v = ip[tid];
        unsigned int vv[4] = {v.x, v.y, v.z, v.w};
#pragma unroll
        for (int q = 0; q < 4; ++q) {
            unsigned int b0 = vv[q] & 255u, b1 = (vv[q] >> 8) & 255u;
            unsigned int b2 = (vv[q] >> 16) & 255u, b3 = vv[q] >> 24;
            t32[sbase + 2 * q] = (b0 > 127u ? SENT : b0 * b0) |
                                 ((b1 > 127u ? SENT : b1 * b1) << 16);
            t32[sbase + 2 * q + 1] = (b2 > 127u ? SENT : b2 * b2) |
                                     ((b3 > 127u ? SENT : b3 * b3) << 16);
        }
    }
    __syncthreads();
    {   // Y phase
        float r[32];
#pragma unroll
        for (int w = 0; w < 32; ++w) r[w] = (float)tile[(iY + w) * TW2 + 8 + z0];
        if (!edt_fast(r, m)) edt_slow<TW2, YD>(&tile[8 * TW2 + 8 + z0], iY, m);
        __syncthreads();
#pragma unroll
        for (int k = 0; k < 16; ++k)
            tile[(8 + iY + k) * TW2 + 8 + z0] =
                (unsigned short)fminf(m[k], (float)SENT);
        __syncthreads();
    }
    {   // Z phase (result kept in regs; no write-back)
        float r[32];
        const unsigned int* wp = &t32[(8 + y0) * TDW + iZ / 2];
#pragma unroll
        for (int q = 0; q < 16; ++q) {
            unsigned int u = wp[q];
            r[2 * q] = (float)(u & 0xFFFFu);
            r[2 * q + 1] = (float)(u >> 16);
        }
        if (!edt_fast(r, m)) edt_slow<1, ZD>(&tile[(8 + y0) * TW2 + 8], iZ, m);
    }
#pragma unroll
    for (int q = 0; q < 8; ++q)
        dpp[q] = (unsigned int)fminf(m[2 * q], (float)SENT) |
                 ((unsigned int)fminf(m[2 * q + 1], (float)SENT) << 16);
    __syncthreads();                     // all pos-plane reads done

    // ================= neg plane (slot 2c+1), same tile =================
    {
        const uint4* ip = (const uint4*)(in + (size_t)(bbl * 6 + 2 * c + 1) * NV +
                                         (size_t)x * SXX);
        uint4 v = ip[tid];
        unsigned int vv[4] = {v.x, v.y, v.z, v.w};
#pragma unroll
        for (int q = 0; q < 4; ++q) {
            unsigned int b0 = vv[q] & 255u, b1 = (vv[q] >> 8) & 255u;
            unsigned int b2 = (vv[q] >> 16) & 255u, b3 = vv[q] >> 24;
            t32[sbase + 2 * q] = (b0 > 127u ? SENT : b0 * b0) |
                                 ((b1 > 127u ? SENT : b1 * b1) << 16);
            t32[sbase + 2 * q + 1] = (b2 > 127u ? SENT : b2 * b2) |
                                     ((b3 > 127u ? SENT : b3 * b3) << 16);
        }
    }
    __syncthreads();
    {   // Y phase
        float r[32];
#pragma unroll
        for (int w = 0; w < 32; ++w) r[w] = (float)tile[(iY + w) * TW2 + 8 + z0];
        if (!edt_fast(r, m)) edt_slow<TW2, YD>(&tile[8 * TW2 + 8 + z0], iY, m);
        __syncthreads();
#pragma unroll
        for (int k = 0; k < 16; ++k)
            tile[(8 + iY + k) * TW2 + 8 + z0] =
                (unsigned short)fminf(m[k], (float)SENT);
        __syncthreads();
    }
    {   // Z phase -> m = dn^2
        float r[32];
        const unsigned int* wp = &t32[(8 + y0) * TDW + iZ / 2];
#pragma unroll
        for (int q = 0; q < 16; ++q) {
            unsigned int u = wp[q];
            r[2 * q] = (float)(u & 0xFFFFu);
            r[2 * q + 1] = (float)(u >> 16);
        }
        if (!edt_fast(r, m)) edt_slow<1, ZD>(&tile[(8 + y0) * TW2 + 8], iZ, m);
    }

    // ================= accumulate p * phi =================
    float a = 0.0f;
    {
        const __half2* pv = probs + (size_t)(b * 3 + c) * (NV / 2) +
                            ((size_t)x * SXX + (size_t)y0 * ZD + iZ) / 2;
#pragma unroll
        for (int q = 0; q < 8; ++q) {
            float2 pf = __half22float2(pv[q]);
            unsigned int dp0 = dpp[q] & 0xFFFFu, dp1 = dpp[q] >> 16;
            float phi0 = (dp0 == 1u) ? 0.0f
                       : (sqrtf(m[2 * q]) - sqrtf((float)dp0));
            float phi1 = (dp1 == 1u) ? 0.0f
                       : (sqrtf(m[2 * q + 1]) - sqrtf((float)dp1));
            a += pf.x * phi0 + pf.y * phi1;
        }
    }
    sd[tid] = (double)a;
    __syncthreads();
    for (int off = 512; off; off >>= 1) {
        if (tid < off && tid + off < 768) sd[tid] += sd[tid + off];
        __syncthreads();
    }
    if (tid == 0) partials[pidx] = sd[0];
}

// -------------------------------------------------------------- reduce ----
__global__ void k_reduce(const double* __restrict__ partials, int n,
                         float* __restrict__ out) {
    __shared__ double sd[256];
    double ls = 0.0;
    for (int i = threadIdx.x; i < n; i += 256) ls += partials[i];
    sd[threadIdx.x] = ls;
    __syncthreads();
    for (int off = 128; off > 0; off >>= 1) {
        if (threadIdx.x < off) sd[threadIdx.x] += sd[threadIdx.x + off];
        __syncthreads();
    }
    if (threadIdx.x == 0) out[0] = (float)(sd[0] / 9437184.0);
}

// ---------------------------------------------------------------- launch ----
extern "C" void kernel_launch(void* const* d_in, const int* in_sizes, int n_in,
                              void* d_out, int out_size, void* d_ws, size_t ws_size,
                              hipStream_t stream) {
    const float* net = (const float*)d_in[0];
    const int*   gt  = (const int*)d_in[1];
    float* out = (float*)d_out;
    char* ws = (char*)d_ws;

    const size_t xbufB1  = (size_t)6 * NV;               // u8 per batch, 9.4 MB
    const size_t probsB  = (size_t)2 * 3 * NV * 2;       // f16, both batches, 18.9 MB
    const size_t tail    = (size_t)768 * sizeof(double) + 64;

    const int nb = (ws_size >= 2 * xbufB1 + probsB + tail) ? 2 : 1;

    unsigned char* xbuf  = (unsigned char*)ws;
    __half2*       probs = (__half2*)(ws + (size_t)nb * xbufB1);
    double*     partials = (double*)(ws + (size_t)nb * xbufB1 + probsB);
    int*           flags = (int*)((char*)partials + 768 * sizeof(double));

    hipLaunchKernelGGL(k_zero_flags, dim3(1), dim3(64), 0, stream, flags);

    for (int b0 = 0; b0 < 2; b0 += nb) {
        hipLaunchKernelGGL(k_scan_x, dim3(SXX / 64, nb), dim3(384), 0, stream,
                           gt, xbuf, flags, b0);
        hipLaunchKernelGGL(k_prob, dim3((NV / 2) / 256, nb), dim3(256), 0,
                           stream, net, probs, b0);
        hipLaunchKernelGGL(k_yz_acc, dim3(XD, 3 * nb), dim3(768), 0, stream,
                           xbuf, probs, flags, partials, b0);
    }
    hipLaunchKernelGGL(k_reduce, dim3(1), dim3(256), 0, stream, partials,
                       768, out);
}

// Round 15
// 78.825 us; speedup vs baseline: 1.1946x; 1.0152x over previous
//
#include <hip/hip_runtime.h>
#include <hip/hip_fp16.h>
#include <math.h>

#define XD 128
#define YD 128
#define ZD 96
#define NV (XD*YD*ZD)      /* 1572864 voxels per volume */
#define SXX (YD*ZD)        /* x-stride = 12288 */
#define SENT 49152         /* sentinel: > any real d^2 (max 41283) */
#define TW2 114            /* u16 cols: 8 pad | 96 z | 10 pad; 57 dw, 57%32=25 */
#define TDW (TW2/2)        /* 57 dwords per row */
#define TROWS 144          /* rows: 8 pad | 128 y | 8 pad */

// ----------- pass X (binary run-length scan) + fused softmax probs ---------
// Waves 0..5: slot w6 = 2*c+s scans (class c+1, sign s) for 64 lines each,
// register-resident, in-wave 4x4 byte transpose for output. Then all threads
// run a grid-stride softmax tail writing f16 probs (overlaps the latency-
// bound scan phase's idle memory system; one dispatch instead of two).
__global__ __launch_bounds__(384) void k_scan_x(const int* __restrict__ gt,
                                                const float* __restrict__ net,
                                                unsigned char* __restrict__ out,
                                                __half2* __restrict__ probs,
                                                int* __restrict__ flags,
                                                int batch0) {
    const int bb  = blockIdx.y;
    const int myb = batch0 + bb;
    const int tid = threadIdx.x;
    const int l   = tid & 63;
    const int w6  = tid >> 6;            // 0..5
    const int lq0 = blockIdx.x * 64;

    __shared__ unsigned char gtile[64 * 132];
    __shared__ int blkbits;
    if (tid == 0) blkbits = 0;

    int mybits = 0;
    const int* gp = gt + (size_t)myb * NV + lq0 + l;
    for (int j = w6; j < XD; j += 6) {
        int g = gp[(size_t)j * SXX];
        mybits |= 1 << g;
        gtile[l * 132 + j] = (unsigned char)g;
    }
#pragma unroll
    for (int off = 32; off; off >>= 1) mybits |= __shfl_xor(mybits, off);
    __syncthreads();
    if ((tid & 63) == 0) atomicOr(&blkbits, mybits);

    unsigned int D[32];
    {   // thread = (slot w6, line l); all in registers
        const unsigned int ci = (unsigned int)((w6 >> 1) + 1);
        const int s = w6 & 1;
        unsigned int G[32];
        const unsigned int* grow = (const unsigned int*)gtile + l * 33;
#pragma unroll
        for (int q = 0; q < 32; ++q) G[q] = grow[q];

        int cnt = 200;
#pragma unroll
        for (int q = 0; q < 32; ++q) {
            unsigned int u = G[q], dv = 0;
#pragma unroll
            for (int b = 0; b < 4; ++b) {
                unsigned int gv = (u >> (8 * b)) & 255u;
                bool zero = s ? (gv == ci) : (gv != ci);
                cnt = zero ? 0 : ((cnt < 200) ? cnt + 1 : 200);
                dv |= (unsigned int)cnt << (8 * b);
            }
            D[q] = dv;
        }
        cnt = 200;
#pragma unroll
        for (int q = 31; q >= 0; --q) {
            unsigned int u = G[q], dv = D[q];
#pragma unroll
            for (int b = 3; b >= 0; --b) {
                unsigned int gv = (u >> (8 * b)) & 255u;
                bool zero = s ? (gv == ci) : (gv != ci);
                cnt = zero ? 0 : ((cnt < 200) ? cnt + 1 : 200);
                unsigned int old = (dv >> (8 * b)) & 255u;
                unsigned int nbv = ((unsigned int)cnt < old) ? (unsigned int)cnt : old;
                dv = (dv & ~(255u << (8 * b))) | (nbv << (8 * b));
            }
            D[q] = dv;
        }
    }
    __syncthreads();                     // blkbits complete
    if (tid == 0) atomicOr(&flags[myb], blkbits);

    // in-wave 4x4 byte transpose (groups of 4 lanes = 4 lines) + store
    {
        const int r = l & 3;
        unsigned char* ob = out + (size_t)(bb * 6 + w6) * NV + lq0 + (l & ~3);
#pragma unroll
        for (int q = 0; q < 32; ++q) {
            unsigned int A = D[q];
            unsigned int Bv = (unsigned int)__shfl_xor((int)A, 1);
            unsigned int t = (r & 1)
                ? __builtin_amdgcn_perm(A, Bv, 0x07030501u)
                : __builtin_amdgcn_perm(A, Bv, 0x02060004u);
            unsigned int Cv = (unsigned int)__shfl_xor((int)t, 2);
            unsigned int y = (r & 2)
                ? __builtin_amdgcn_perm(t, Cv, 0x07060302u)
                : __builtin_amdgcn_perm(t, Cv, 0x01000504u);
            *(unsigned int*)(ob + (size_t)(4 * q + r) * SXX) = y;
        }
    }

    // ---- fused softmax tail: grid-stride over this batch's voxel pairs ----
    {
        const float* nb = net + (size_t)myb * 4 * NV;
        for (int p = blockIdx.x * 384 + tid; p < NV / 2; p += 192 * 384) {
            const int idx = p * 2;
            float2 v0 = *(const float2*)(nb + idx);
            float2 v1 = *(const float2*)(nb + NV + idx);
            float2 v2 = *(const float2*)(nb + 2 * NV + idx);
            float2 v3 = *(const float2*)(nb + 3 * NV + idx);

            float mxa = fmaxf(fmaxf(v0.x, v1.x), fmaxf(v2.x, v3.x));
            float mxb = fmaxf(fmaxf(v0.y, v1.y), fmaxf(v2.y, v3.y));
            float e1a = __expf(v1.x - mxa), e2a = __expf(v2.x - mxa), e3a = __expf(v3.x - mxa);
            float e1b = __expf(v1.y - mxb), e2b = __expf(v2.y - mxb), e3b = __expf(v3.y - mxb);
            float sa = __expf(v0.x - mxa) + e1a + e2a + e3a;
            float sb = __expf(v0.y - mxb) + e1b + e2b + e3b;
            float ia = __frcp_rn(sa), ib = __frcp_rn(sb);

            probs[(size_t)(myb * 3 + 0) * (NV / 2) + p] = __floats2half2_rn(e1a * ia, e1b * ib);
            probs[(size_t)(myb * 3 + 1) * (NV / 2) + p] = __floats2half2_rn(e2a * ia, e2b * ib);
            probs[(size_t)(myb * 3 + 2) * (NV / 2) + p] = __floats2half2_rn(e3a * ia, e3b * ib);
        }
    }
}

// ------------- EDT fast path: t<=8 on a 32-float register window -----------
__device__ __forceinline__ bool edt_fast(const float r[32], float m[16]) {
#pragma unroll
    for (int k = 0; k < 16; ++k) m[k] = r[k + 8];
#pragma unroll
    for (int t = 1; t <= 4; ++t) {
        const float t2 = (float)(t * t);
#pragma unroll
        for (int k = 0; k < 16; ++k)
            m[k] = fminf(m[k], fminf(r[k + 8 - t], r[k + 8 + t]) + t2);
    }
    float mm = m[0];
#pragma unroll
    for (int k = 1; k < 16; ++k) mm = fmaxf(mm, m[k]);
    if (__all(mm <= 16.0f)) return true;
#pragma unroll
    for (int t = 5; t <= 8; ++t) {
        const float t2 = (float)(t * t);
#pragma unroll
        for (int k = 0; k < 16; ++k)
            m[k] = fminf(m[k], fminf(r[k + 8 - t], r[k + 8 + t]) + t2);
    }
    mm = m[0];
#pragma unroll
    for (int k = 1; k < 16; ++k) mm = fmaxf(mm, m[k]);
    return __all(mm <= 64.0f) != 0;
}

// ------------- EDT slow path (rare): clamped LDS u16 reads, t>=9 -----------
template<int STRIDE, int L>
__device__ void edt_slow(const unsigned short* __restrict__ p0, int i0,
                         float m[16]) {
    int t = 9;
    bool done = false;
    while (!done && t < L) {
        for (int u = 0; u < 4; ++u, ++t) {
            float t2 = (float)(t * t);
#pragma unroll
            for (int k = 0; k < 16; ++k) {
                int jm = i0 + k - t; if (jm < -8) jm = -8;
                int jp = i0 + k + t; if (jp > L + 7) jp = L + 7;
                m[k] = fminf(m[k], fminf((float)p0[jm * STRIDE],
                                         (float)p0[jp * STRIDE]) + t2);
            }
        }
        float mm = m[0];
#pragma unroll
        for (int k = 1; k < 16; ++k) mm = fmaxf(mm, m[k]);
        done = __all(mm <= (float)((t - 1) * (t - 1))) != 0;
    }
}

// ------ fused Y+Z EDT + loss accumulation: one (x, class, batch) block -----
// Single u16 [y][z] tile (32.8 KB; pads survive re-staging). Sequence:
// stage pos -> EDT -> pack dp^2 into 8 VGPRs -> re-stage neg in SAME tile ->
// EDT -> phi = (dp==1)?0:sqrt(dn)-sqrt(dp) -> p*phi block-reduce.
__global__ __launch_bounds__(768, 6) void k_yz_acc(const unsigned char* __restrict__ in,
                                                   const __half2* __restrict__ probs,
                                                   const int* __restrict__ flags,
                                                   double* __restrict__ partials,
                                                   int batch0) {
    const int x   = blockIdx.x;
    const int bbl = blockIdx.y / 3;      // local batch (xbuf slot group)
    const int c   = blockIdx.y % 3;      // class-1
    const int b   = batch0 + bbl;        // global batch
    const int tid = threadIdx.x;
    const int pidx = (b * 3 + c) * XD + x;

    __shared__ unsigned short tile[TROWS * TW2];
    __shared__ double sd[768];
    unsigned int* t32 = (unsigned int*)tile;

    if (((flags[b] >> (c + 1)) & 1) == 0) {
        if (tid == 0) partials[pidx] = 0.0;
        return;
    }

    // pads (once; EDT write-backs and re-staging touch only data cells)
    for (int i = tid; i < 16 * TDW; i += 768) {
        int r = i / TDW, cc = i - r * TDW;
        int row = (r < 8) ? r : 128 + r;
        t32[row * TDW + cc] = 0xFFFFFFFFu;
    }
    for (int i = tid; i < 128 * 9; i += 768) {
        int r = i / 9, cc = i - r * 9;
        int col = (cc < 4) ? cc : (48 + cc);
        t32[(8 + r) * TDW + col] = 0xFFFFFFFFu;
    }

    const int z0 = tid % 96;  const int iY = (tid / 96) * 16;
    const int y0 = tid % 128; const int iZ = (tid / 128) * 16;
    const int e  = tid * 16;
    const int sy = e / ZD, sz = e - sy * ZD;
    const unsigned int sbase = (8 + sy) * TDW + (8 + sz) / 2;

    float m[16];
    unsigned int dpp[8];

    // ================= pos plane (slot 2c) =================
    {
        const uint4* ip = (const uint4*)(in + (size_t)(bbl * 6 + 2 * c) * NV +
                                         (size_t)x * SXX);
        uint4 v = ip[tid];
        unsigned int vv[4] = {v.x, v.y, v.z, v.w};
#pragma unroll
        for (int q = 0; q < 4; ++q) {
            unsigned int b0 = vv[q] & 255u, b1 = (vv[q] >> 8) & 255u;
            unsigned int b2 = (vv[q] >> 16) & 255u, b3 = vv[q] >> 24;
            t32[sbase + 2 * q] = (b0 > 127u ? SENT : b0 * b0) |
                                 ((b1 > 127u ? SENT : b1 * b1) << 16);
            t32[sbase + 2 * q + 1] = (b2 > 127u ? SENT : b2 * b2) |
                                     ((b3 > 127u ? SENT : b3 * b3) << 16);
        }
    }
    __syncthreads();
    {   // Y phase
        float r[32];
#pragma unroll
        for (int w = 0; w < 32; ++w) r[w] = (float)tile[(iY + w) * TW2 + 8 + z0];
        if (!edt_fast(r, m)) edt_slow<TW2, YD>(&tile[8 * TW2 + 8 + z0], iY, m);
        __syncthreads();
#pragma unroll
        for (int k = 0; k < 16; ++k)
            tile[(8 + iY + k) * TW2 + 8 + z0] =
                (unsigned short)fminf(m[k], (float)SENT);
        __syncthreads();
    }
    {   // Z phase (result kept in regs; no write-back)
        float r[32];
        const unsigned int* wp = &t32[(8 + y0) * TDW + iZ / 2];
#pragma unroll
        for (int q = 0; q < 16; ++q) {
            unsigned int u = wp[q];
            r[2 * q] = (float)(u & 0xFFFFu);
            r[2 * q + 1] = (float)(u >> 16);
        }
        if (!edt_fast(r, m)) edt_slow<1, ZD>(&tile[(8 + y0) * TW2 + 8], iZ, m);
    }
#pragma unroll
    for (int q = 0; q < 8; ++q)
        dpp[q] = (unsigned int)fminf(m[2 * q], (float)SENT) |
                 ((unsigned int)fminf(m[2 * q + 1], (float)SENT) << 16);
    __syncthreads();                     // all pos-plane reads done

    // ================= neg plane (slot 2c+1), same tile =================
    {
        const uint4* ip = (const uint4*)(in + (size_t)(bbl * 6 + 2 * c + 1) * NV +
                                         (size_t)x * SXX);
        uint4 v = ip[tid];
        unsigned int vv[4] = {v.x, v.y, v.z, v.w};
#pragma unroll
        for (int q = 0; q < 4; ++q) {
            unsigned int b0 = vv[q] & 255u, b1 = (vv[q] >> 8) & 255u;
            unsigned int b2 = (vv[q] >> 16) & 255u, b3 = vv[q] >> 24;
            t32[sbase + 2 * q] = (b0 > 127u ? SENT : b0 * b0) |
                                 ((b1 > 127u ? SENT : b1 * b1) << 16);
            t32[sbase + 2 * q + 1] = (b2 > 127u ? SENT : b2 * b2) |
                                     ((b3 > 127u ? SENT : b3 * b3) << 16);
        }
    }
    __syncthreads();
    {   // Y phase
        float r[32];
#pragma unroll
        for (int w = 0; w < 32; ++w) r[w] = (float)tile[(iY + w) * TW2 + 8 + z0];
        if (!edt_fast(r, m)) edt_slow<TW2, YD>(&tile[8 * TW2 + 8 + z0], iY, m);
        __syncthreads();
#pragma unroll
        for (int k = 0; k < 16; ++k)
            tile[(8 + iY + k) * TW2 + 8 + z0] =
                (unsigned short)fminf(m[k], (float)SENT);
        __syncthreads();
    }
    {   // Z phase -> m = dn^2
        float r[32];
        const unsigned int* wp = &t32[(8 + y0) * TDW + iZ / 2];
#pragma unroll
        for (int q = 0; q < 16; ++q) {
            unsigned int u = wp[q];
            r[2 * q] = (float)(u & 0xFFFFu);
            r[2 * q + 1] = (float)(u >> 16);
        }
        if (!edt_fast(r, m)) edt_slow<1, ZD>(&tile[(8 + y0) * TW2 + 8], iZ, m);
    }

    // ================= accumulate p * phi =================
    float a = 0.0f;
    {
        const __half2* pv = probs + (size_t)(b * 3 + c) * (NV / 2) +
                            ((size_t)x * SXX + (size_t)y0 * ZD + iZ) / 2;
#pragma unroll
        for (int q = 0; q < 8; ++q) {
            float2 pf = __half22float2(pv[q]);
            unsigned int dp0 = dpp[q] & 0xFFFFu, dp1 = dpp[q] >> 16;
            float phi0 = (dp0 == 1u) ? 0.0f
                       : (sqrtf(m[2 * q]) - sqrtf((float)dp0));
            float phi1 = (dp1 == 1u) ? 0.0f
                       : (sqrtf(m[2 * q + 1]) - sqrtf((float)dp1));
            a += pf.x * phi0 + pf.y * phi1;
        }
    }
    sd[tid] = (double)a;
    __syncthreads();
    for (int off = 512; off; off >>= 1) {
        if (tid < off && tid + off < 768) sd[tid] += sd[tid + off];
        __syncthreads();
    }
    if (tid == 0) partials[pidx] = sd[0];
}

// -------------------------------------------------------------- reduce ----
__global__ void k_reduce(const double* __restrict__ partials, int n,
                         float* __restrict__ out) {
    __shared__ double sd[256];
    double ls = 0.0;
    for (int i = threadIdx.x; i < n; i += 256) ls += partials[i];
    sd[threadIdx.x] = ls;
    __syncthreads();
    for (int off = 128; off > 0; off >>= 1) {
        if (threadIdx.x < off) sd[threadIdx.x] += sd[threadIdx.x + off];
        __syncthreads();
    }
    if (threadIdx.x == 0) out[0] = (float)(sd[0] / 9437184.0);
}

// ---------------------------------------------------------------- launch ----
extern "C" void kernel_launch(void* const* d_in, const int* in_sizes, int n_in,
                              void* d_out, int out_size, void* d_ws, size_t ws_size,
                              hipStream_t stream) {
    const float* net = (const float*)d_in[0];
    const int*   gt  = (const int*)d_in[1];
    float* out = (float*)d_out;
    char* ws = (char*)d_ws;

    const size_t xbufB1  = (size_t)6 * NV;               // u8 per batch, 9.4 MB
    const size_t probsB  = (size_t)2 * 3 * NV * 2;       // f16, both batches, 18.9 MB
    const size_t tail    = (size_t)768 * sizeof(double) + 64;

    const int nb = (ws_size >= 2 * xbufB1 + probsB + tail) ? 2 : 1;

    unsigned char* xbuf  = (unsigned char*)ws;
    __half2*       probs = (__half2*)(ws + (size_t)nb * xbufB1);
    double*     partials = (double*)(ws + (size_t)nb * xbufB1 + probsB);
    int*           flags = (int*)((char*)partials + 768 * sizeof(double));

    hipMemsetAsync(flags, 0, 8 * sizeof(int), stream);

    for (int b0 = 0; b0 < 2; b0 += nb) {
        hipLaunchKernelGGL(k_scan_x, dim3(SXX / 64, nb), dim3(384), 0, stream,
                           gt, net, xbuf, probs, flags, b0);
        hipLaunchKernelGGL(k_yz_acc, dim3(XD, 3 * nb), dim3(768), 0, stream,
                           xbuf, probs, flags, partials, b0);
    }
    hipLaunchKernelGGL(k_reduce, dim3(1), dim3(256), 0, stream, partials,
                       768, out);
}

// Round 16
// 70.030 us; speedup vs baseline: 1.3446x; 1.1256x over previous
//
#include <hip/hip_runtime.h>
#include <hip/hip_fp16.h>
#include <math.h>

#define XD 128
#define YD 128
#define ZD 96
#define NV (XD*YD*ZD)      /* 1572864 voxels per volume */
#define SXX (YD*ZD)        /* x-stride = 12288 */
#define SENT 49152         /* sentinel: > any real d^2 (max 41283) */
#define TW2 114            /* u16 cols: 8 pad | 96 z | 10 pad; 57 dw, 57%32=25 */
#define TDW (TW2/2)        /* 57 dwords per row */
#define TROWS 144          /* rows: 8 pad | 128 y | 8 pad */
#define SCANB 192          /* scan blocks per batch */
#define PROBB 1024         /* prob blocks per batch: 1024*384 = NV/4 exactly */

// -------- block-specialized: scan blocks + softmax blocks, one dispatch ----
// Blocks x<SCANB: binary run-length x-scan (register-resident, in-wave 4x4
// byte transpose). Blocks x>=SCANB: softmax, one float4 quad per thread.
// Roles are independent (both read-only on gt/net); co-residency lets the
// BW-bound prob blocks fill the machine while scan waves hide latency.
__global__ __launch_bounds__(384) void k_scan_prob(const int* __restrict__ gt,
                                                   const float* __restrict__ net,
                                                   unsigned char* __restrict__ out,
                                                   __half2* __restrict__ probs,
                                                   int* __restrict__ flags,
                                                   int batch0) {
    const int bb  = blockIdx.y;
    const int myb = batch0 + bb;
    const int tid = threadIdx.x;

    if (blockIdx.x >= SCANB) {           // ---------------- prob role ----
        const int p = (blockIdx.x - SCANB) * 384 + tid;   // quad index < NV/4
        const int idx = p * 4;
        const float* nb = net + (size_t)myb * 4 * NV;
        float4 v0 = *(const float4*)(nb + idx);
        float4 v1 = *(const float4*)(nb + NV + idx);
        float4 v2 = *(const float4*)(nb + 2 * NV + idx);
        float4 v3 = *(const float4*)(nb + 3 * NV + idx);

        const float a0[4] = {v0.x, v0.y, v0.z, v0.w};
        const float a1[4] = {v1.x, v1.y, v1.z, v1.w};
        const float a2[4] = {v2.x, v2.y, v2.z, v2.w};
        const float a3[4] = {v3.x, v3.y, v3.z, v3.w};
        float p1[4], p2[4], p3[4];
#pragma unroll
        for (int j = 0; j < 4; ++j) {
            float mx = fmaxf(fmaxf(a0[j], a1[j]), fmaxf(a2[j], a3[j]));
            float e0 = __expf(a0[j] - mx);
            float e1 = __expf(a1[j] - mx);
            float e2 = __expf(a2[j] - mx);
            float e3 = __expf(a3[j] - mx);
            float iv = __frcp_rn(e0 + e1 + e2 + e3);
            p1[j] = e1 * iv; p2[j] = e2 * iv; p3[j] = e3 * iv;
        }
        __half2 h10 = __floats2half2_rn(p1[0], p1[1]);
        __half2 h11 = __floats2half2_rn(p1[2], p1[3]);
        __half2 h20 = __floats2half2_rn(p2[0], p2[1]);
        __half2 h21 = __floats2half2_rn(p2[2], p2[3]);
        __half2 h30 = __floats2half2_rn(p3[0], p3[1]);
        __half2 h31 = __floats2half2_rn(p3[2], p3[3]);
        ((__half2*)probs)[(size_t)(myb * 3 + 0) * (NV / 2) + 2 * p]     = h10;
        ((__half2*)probs)[(size_t)(myb * 3 + 0) * (NV / 2) + 2 * p + 1] = h11;
        ((__half2*)probs)[(size_t)(myb * 3 + 1) * (NV / 2) + 2 * p]     = h20;
        ((__half2*)probs)[(size_t)(myb * 3 + 1) * (NV / 2) + 2 * p + 1] = h21;
        ((__half2*)probs)[(size_t)(myb * 3 + 2) * (NV / 2) + 2 * p]     = h30;
        ((__half2*)probs)[(size_t)(myb * 3 + 2) * (NV / 2) + 2 * p + 1] = h31;
        return;
    }

    // ---------------- scan role ----
    const int l   = tid & 63;
    const int w6  = tid >> 6;            // 0..5
    const int lq0 = blockIdx.x * 64;

    __shared__ unsigned char gtile[64 * 132];
    __shared__ int blkbits;
    if (tid == 0) blkbits = 0;

    int mybits = 0;
    const int* gp = gt + (size_t)myb * NV + lq0 + l;
    for (int j = w6; j < XD; j += 6) {
        int g = gp[(size_t)j * SXX];
        mybits |= 1 << g;
        gtile[l * 132 + j] = (unsigned char)g;
    }
#pragma unroll
    for (int off = 32; off; off >>= 1) mybits |= __shfl_xor(mybits, off);
    __syncthreads();
    if ((tid & 63) == 0) atomicOr(&blkbits, mybits);

    unsigned int D[32];
    {   // thread = (slot w6, line l); all in registers
        const unsigned int ci = (unsigned int)((w6 >> 1) + 1);
        const int s = w6 & 1;
        unsigned int G[32];
        const unsigned int* grow = (const unsigned int*)gtile + l * 33;
#pragma unroll
        for (int q = 0; q < 32; ++q) G[q] = grow[q];

        int cnt = 200;
#pragma unroll
        for (int q = 0; q < 32; ++q) {
            unsigned int u = G[q], dv = 0;
#pragma unroll
            for (int b = 0; b < 4; ++b) {
                unsigned int gv = (u >> (8 * b)) & 255u;
                bool zero = s ? (gv == ci) : (gv != ci);
                cnt = zero ? 0 : ((cnt < 200) ? cnt + 1 : 200);
                dv |= (unsigned int)cnt << (8 * b);
            }
            D[q] = dv;
        }
        cnt = 200;
#pragma unroll
        for (int q = 31; q >= 0; --q) {
            unsigned int u = G[q], dv = D[q];
#pragma unroll
            for (int b = 3; b >= 0; --b) {
                unsigned int gv = (u >> (8 * b)) & 255u;
                bool zero = s ? (gv == ci) : (gv != ci);
                cnt = zero ? 0 : ((cnt < 200) ? cnt + 1 : 200);
                unsigned int old = (dv >> (8 * b)) & 255u;
                unsigned int nbv = ((unsigned int)cnt < old) ? (unsigned int)cnt : old;
                dv = (dv & ~(255u << (8 * b))) | (nbv << (8 * b));
            }
            D[q] = dv;
        }
    }
    __syncthreads();                     // blkbits complete
    if (tid == 0) atomicOr(&flags[myb], blkbits);

    // in-wave 4x4 byte transpose (groups of 4 lanes = 4 lines) + store
    {
        const int r = l & 3;
        unsigned char* ob = out + (size_t)(bb * 6 + w6) * NV + lq0 + (l & ~3);
#pragma unroll
        for (int q = 0; q < 32; ++q) {
            unsigned int A = D[q];
            unsigned int Bv = (unsigned int)__shfl_xor((int)A, 1);
            unsigned int t = (r & 1)
                ? __builtin_amdgcn_perm(A, Bv, 0x07030501u)
                : __builtin_amdgcn_perm(A, Bv, 0x02060004u);
            unsigned int Cv = (unsigned int)__shfl_xor((int)t, 2);
            unsigned int y = (r & 2)
                ? __builtin_amdgcn_perm(t, Cv, 0x07060302u)
                : __builtin_amdgcn_perm(t, Cv, 0x01000504u);
            *(unsigned int*)(ob + (size_t)(4 * q + r) * SXX) = y;
        }
    }
}

// ------------- EDT fast path: t<=8 on a 32-float register window -----------
__device__ __forceinline__ bool edt_fast(const float r[32], float m[16]) {
#pragma unroll
    for (int k = 0; k < 16; ++k) m[k] = r[k + 8];
#pragma unroll
    for (int t = 1; t <= 4; ++t) {
        const float t2 = (float)(t * t);
#pragma unroll
        for (int k = 0; k < 16; ++k)
            m[k] = fminf(m[k], fminf(r[k + 8 - t], r[k + 8 + t]) + t2);
    }
    float mm = m[0];
#pragma unroll
    for (int k = 1; k < 16; ++k) mm = fmaxf(mm, m[k]);
    if (__all(mm <= 16.0f)) return true;
#pragma unroll
    for (int t = 5; t <= 8; ++t) {
        const float t2 = (float)(t * t);
#pragma unroll
        for (int k = 0; k < 16; ++k)
            m[k] = fminf(m[k], fminf(r[k + 8 - t], r[k + 8 + t]) + t2);
    }
    mm = m[0];
#pragma unroll
    for (int k = 1; k < 16; ++k) mm = fmaxf(mm, m[k]);
    return __all(mm <= 64.0f) != 0;
}

// ------------- EDT slow path (rare): clamped LDS u16 reads, t>=9 -----------
template<int STRIDE, int L>
__device__ void edt_slow(const unsigned short* __restrict__ p0, int i0,
                         float m[16]) {
    int t = 9;
    bool done = false;
    while (!done && t < L) {
        for (int u = 0; u < 4; ++u, ++t) {
            float t2 = (float)(t * t);
#pragma unroll
            for (int k = 0; k < 16; ++k) {
                int jm = i0 + k - t; if (jm < -8) jm = -8;
                int jp = i0 + k + t; if (jp > L + 7) jp = L + 7;
                m[k] = fminf(m[k], fminf((float)p0[jm * STRIDE],
                                         (float)p0[jp * STRIDE]) + t2);
            }
        }
        float mm = m[0];
#pragma unroll
        for (int k = 1; k < 16; ++k) mm = fmaxf(mm, m[k]);
        done = __all(mm <= (float)((t - 1) * (t - 1))) != 0;
    }
}

// ------ fused Y+Z EDT + loss accumulation: one (x, class, batch) block -----
__global__ __launch_bounds__(768, 6) void k_yz_acc(const unsigned char* __restrict__ in,
                                                   const __half2* __restrict__ probs,
                                                   const int* __restrict__ flags,
                                                   double* __restrict__ partials,
                                                   int batch0) {
    const int x   = blockIdx.x;
    const int bbl = blockIdx.y / 3;      // local batch (xbuf slot group)
    const int c   = blockIdx.y % 3;      // class-1
    const int b   = batch0 + bbl;        // global batch
    const int tid = threadIdx.x;
    const int pidx = (b * 3 + c) * XD + x;

    __shared__ unsigned short tile[TROWS * TW2];
    __shared__ double sd[768];
    unsigned int* t32 = (unsigned int*)tile;

    if (((flags[b] >> (c + 1)) & 1) == 0) {
        if (tid == 0) partials[pidx] = 0.0;
        return;
    }

    for (int i = tid; i < 16 * TDW; i += 768) {
        int r = i / TDW, cc = i - r * TDW;
        int row = (r < 8) ? r : 128 + r;
        t32[row * TDW + cc] = 0xFFFFFFFFu;
    }
    for (int i = tid; i < 128 * 9; i += 768) {
        int r = i / 9, cc = i - r * 9;
        int col = (cc < 4) ? cc : (48 + cc);
        t32[(8 + r) * TDW + col] = 0xFFFFFFFFu;
    }

    const int z0 = tid % 96;  const int iY = (tid / 96) * 16;
    const int y0 = tid % 128; const int iZ = (tid / 128) * 16;
    const int e  = tid * 16;
    const int sy = e / ZD, sz = e - sy * ZD;
    const unsigned int sbase = (8 + sy) * TDW + (8 + sz) / 2;

    float m[16];
    unsigned int dpp[8];

    // ================= pos plane (slot 2c) =================
    {
        const uint4* ip = (const uint4*)(in + (size_t)(bbl * 6 + 2 * c) * NV +
                                         (size_t)x * SXX);
        uint4 v = ip[tid];
        unsigned int vv[4] = {v.x, v.y, v.z, v.w};
#pragma unroll
        for (int q = 0; q < 4; ++q) {
            unsigned int b0 = vv[q] & 255u, b1 = (vv[q] >> 8) & 255u;
            unsigned int b2 = (vv[q] >> 16) & 255u, b3 = vv[q] >> 24;
            t32[sbase + 2 * q] = (b0 > 127u ? SENT : b0 * b0) |
                                 ((b1 > 127u ? SENT : b1 * b1) << 16);
            t32[sbase + 2 * q + 1] = (b2 > 127u ? SENT : b2 * b2) |
                                     ((b3 > 127u ? SENT : b3 * b3) << 16);
        }
    }
    __syncthreads();
    {   // Y phase
        float r[32];
#pragma unroll
        for (int w = 0; w < 32; ++w) r[w] = (float)tile[(iY + w) * TW2 + 8 + z0];
        if (!edt_fast(r, m)) edt_slow<TW2, YD>(&tile[8 * TW2 + 8 + z0], iY, m);
        __syncthreads();
#pragma unroll
        for (int k = 0; k < 16; ++k)
            tile[(8 + iY + k) * TW2 + 8 + z0] =
                (unsigned short)fminf(m[k], (float)SENT);
        __syncthreads();
    }
    {   // Z phase (result kept in regs; no write-back)
        float r[32];
        const unsigned int* wp = &t32[(8 + y0) * TDW + iZ / 2];
#pragma unroll
        for (int q = 0; q < 16; ++q) {
            unsigned int u = wp[q];
            r[2 * q] = (float)(u & 0xFFFFu);
            r[2 * q + 1] = (float)(u >> 16);
        }
        if (!edt_fast(r, m)) edt_slow<1, ZD>(&tile[(8 + y0) * TW2 + 8], iZ, m);
    }
#pragma unroll
    for (int q = 0; q < 8; ++q)
        dpp[q] = (unsigned int)fminf(m[2 * q], (float)SENT) |
                 ((unsigned int)fminf(m[2 * q + 1], (float)SENT) << 16);
    __syncthreads();                     // all pos-plane reads done

    // ================= neg plane (slot 2c+1), same tile =================
    {
        const uint4* ip = (const uint4*)(in + (size_t)(bbl * 6 + 2 * c + 1) * NV +
                                         (size_t)x * SXX);
        uint4 v = ip[tid];
        unsigned int vv[4] = {v.x, v.y, v.z, v.w};
#pragma unroll
        for (int q = 0; q < 4; ++q) {
            unsigned int b0 = vv[q] & 255u, b1 = (vv[q] >> 8) & 255u;
            unsigned int b2 = (vv[q] >> 16) & 255u, b3 = vv[q] >> 24;
            t32[sbase + 2 * q] = (b0 > 127u ? SENT : b0 * b0) |
                                 ((b1 > 127u ? SENT : b1 * b1) << 16);
            t32[sbase + 2 * q + 1] = (b2 > 127u ? SENT : b2 * b2) |
                                     ((b3 > 127u ? SENT : b3 * b3) << 16);
        }
    }
    __syncthreads();
    {   // Y phase
        float r[32];
#pragma unroll
        for (int w = 0; w < 32; ++w) r[w] = (float)tile[(iY + w) * TW2 + 8 + z0];
        if (!edt_fast(r, m)) edt_slow<TW2, YD>(&tile[8 * TW2 + 8 + z0], iY, m);
        __syncthreads();
#pragma unroll
        for (int k = 0; k < 16; ++k)
            tile[(8 + iY + k) * TW2 + 8 + z0] =
                (unsigned short)fminf(m[k], (float)SENT);
        __syncthreads();
    }
    {   // Z phase -> m = dn^2
        float r[32];
        const unsigned int* wp = &t32[(8 + y0) * TDW + iZ / 2];
#pragma unroll
        for (int q = 0; q < 16; ++q) {
            unsigned int u = wp[q];
            r[2 * q] = (float)(u & 0xFFFFu);
            r[2 * q + 1] = (float)(u >> 16);
        }
        if (!edt_fast(r, m)) edt_slow<1, ZD>(&tile[(8 + y0) * TW2 + 8], iZ, m);
    }

    // ================= accumulate p * phi =================
    float a = 0.0f;
    {
        const __half2* pv = probs + (size_t)(b * 3 + c) * (NV / 2) +
                            ((size_t)x * SXX + (size_t)y0 * ZD + iZ) / 2;
#pragma unroll
        for (int q = 0; q < 8; ++q) {
            float2 pf = __half22float2(pv[q]);
            unsigned int dp0 = dpp[q] & 0xFFFFu, dp1 = dpp[q] >> 16;
            float phi0 = (dp0 == 1u) ? 0.0f
                       : (sqrtf(m[2 * q]) - sqrtf((float)dp0));
            float phi1 = (dp1 == 1u) ? 0.0f
                       : (sqrtf(m[2 * q + 1]) - sqrtf((float)dp1));
            a += pf.x * phi0 + pf.y * phi1;
        }
    }
    sd[tid] = (double)a;
    __syncthreads();
    for (int off = 512; off; off >>= 1) {
        if (tid < off && tid + off < 768) sd[tid] += sd[tid + off];
        __syncthreads();
    }
    if (tid == 0) partials[pidx] = sd[0];
}

// -------------------------------------------------------------- reduce ----
__global__ void k_reduce(const double* __restrict__ partials, int n,
                         float* __restrict__ out) {
    __shared__ double sd[256];
    double ls = 0.0;
    for (int i = threadIdx.x; i < n; i += 256) ls += partials[i];
    sd[threadIdx.x] = ls;
    __syncthreads();
    for (int off = 128; off > 0; off >>= 1) {
        if (threadIdx.x < off) sd[threadIdx.x] += sd[threadIdx.x + off];
        __syncthreads();
    }
    if (threadIdx.x == 0) out[0] = (float)(sd[0] / 9437184.0);
}

// ---------------------------------------------------------------- launch ----
extern "C" void kernel_launch(void* const* d_in, const int* in_sizes, int n_in,
                              void* d_out, int out_size, void* d_ws, size_t ws_size,
                              hipStream_t stream) {
    const float* net = (const float*)d_in[0];
    const int*   gt  = (const int*)d_in[1];
    float* out = (float*)d_out;
    char* ws = (char*)d_ws;

    const size_t xbufB1  = (size_t)6 * NV;               // u8 per batch, 9.4 MB
    const size_t probsB  = (size_t)2 * 3 * NV * 2;       // f16, both batches, 18.9 MB
    const size_t tail    = (size_t)768 * sizeof(double) + 64;

    const int nb = (ws_size >= 2 * xbufB1 + probsB + tail) ? 2 : 1;

    unsigned char* xbuf  = (unsigned char*)ws;
    __half2*       probs = (__half2*)(ws + (size_t)nb * xbufB1);
    double*     partials = (double*)(ws + (size_t)nb * xbufB1 + probsB);
    int*           flags = (int*)((char*)partials + 768 * sizeof(double));

    hipMemsetAsync(flags, 0, 8 * sizeof(int), stream);

    for (int b0 = 0; b0 < 2; b0 += nb) {
        hipLaunchKernelGGL(k_scan_prob, dim3(SCANB + PROBB, nb), dim3(384), 0,
                           stream, gt, net, xbuf, probs, flags, b0);
        hipLaunchKernelGGL(k_yz_acc, dim3(XD, 3 * nb), dim3(768), 0, stream,
                           xbuf, probs, flags, partials, b0);
    }
    hipLaunchKernelGGL(k_reduce, dim3(1), dim3(256), 0, stream, partials,
                       768, out);
}